// Round 1
// baseline (1139.120 us; speedup 1.0000x reference)
//
#include <hip/hip_runtime.h>
#include <math.h>

#define BATCH 2
#define NPTS  4096
#define DFEAT 384
#define DCODE 90
#define KNN   7
#define INV_T 10.0f     // 1/temperature
#define LAMBDA 0.3f

// ---------------------------------------------------------------------------
// helpers
// ---------------------------------------------------------------------------
__device__ __forceinline__ void fma4(float4 a, float4 t0, float4 t1, float4 t2,
                                     float4 t3, float* acc) {
  // acc[j] += sum over 4 d's of f[d] * tile[d][m0+j]
  acc[0] += a.x * t0.x + a.y * t1.x + a.z * t2.x + a.w * t3.x;
  acc[1] += a.x * t0.y + a.y * t1.y + a.z * t2.y + a.w * t3.y;
  acc[2] += a.x * t0.z + a.y * t1.z + a.z * t2.z + a.w * t3.z;
  acc[3] += a.x * t0.w + a.y * t1.w + a.z * t2.w + a.w * t3.w;
}

// top-7 insertion with fully static register indexing (rule #20: dynamic
// indexing would spill to scratch; unrolled predicated writes stay in VGPRs)
__device__ __forceinline__ void top7_insert(float v, int i, float* v7, int* i7,
                                            float& vmin, int& pmin) {
  if (v > vmin) {
#pragma unroll
    for (int t = 0; t < KNN; ++t) {
      if (t == pmin) { v7[t] = v; i7[t] = i; }
    }
    vmin = v7[0]; pmin = 0;
#pragma unroll
    for (int t = 1; t < KNN; ++t) {
      if (v7[t] < vmin) { vmin = v7[t]; pmin = t; }
    }
  }
}

// ---------------------------------------------------------------------------
// K1: inverse norms of feature rows (384) and code rows (90)
// ---------------------------------------------------------------------------
__global__ void norms_kernel(const float* __restrict__ codes,
                             const float* __restrict__ feats,
                             float* __restrict__ invc,
                             float* __restrict__ invf) {
  const int row = blockIdx.x;  // 0 .. B*N-1
  const int tid = threadIdx.x;
  const float* f = feats + (size_t)row * DFEAT;
  const float* c = codes + (size_t)row * DCODE;
  float sf = 0.f, sc = 0.f;
  for (int d = tid; d < DFEAT; d += 256) { float v = f[d]; sf += v * v; }
  if (tid < DCODE) { float v = c[tid]; sc = v * v; }
  __shared__ float rf[256], rc[256];
  rf[tid] = sf; rc[tid] = sc;
  __syncthreads();
  for (int s = 128; s > 0; s >>= 1) {
    if (tid < s) { rf[tid] += rf[tid + s]; rc[tid] += rc[tid + s]; }
    __syncthreads();
  }
  if (tid == 0) {
    invf[row] = 1.0f / sqrtf(rf[0] + 1e-8f);
    invc[row] = 1.0f / sqrtf(rc[0] + 1e-8f);
  }
}

// ---------------------------------------------------------------------------
// K2: feature similarities + per-row top-7 indices
// block: 256 thr, 16 q-rows; m-tiles of 128, d-chunks of 64 staged [d][m] in LDS
// thread tile: 2 rows x 4 m  (tidy=tid>>5 -> rows 2*tidy,2*tidy+1; tidx=tid&31)
// ---------------------------------------------------------------------------
__global__ __launch_bounds__(256, 2)
void knn_kernel(const float* __restrict__ feats, const float* __restrict__ invf,
                int* __restrict__ knn_out) {
  __shared__ alignas(16) float smem[16 * 392 + 64 * 128 + 128];
  float* frows = smem;                          // [16][392] q rows (raw)
  float* tileT = smem + 16 * 392;               // [64][128]  tile[d][m]
  float* invm  = smem + 16 * 392 + 64 * 128;    // [128]

  const int tid = threadIdx.x;
  const int b   = blockIdx.x >> 8;              // 256 blocks per batch
  const int n0  = (blockIdx.x & 255) * 16;
  const float* Fb    = feats + (size_t)b * NPTS * DFEAT;
  const float* invfb = invf + b * NPTS;

  // stage 16 q-rows: 16*96 float4
#pragma unroll
  for (int k = 0; k < 6; ++k) {
    int idx = tid + k * 256;
    int r = idx / 96, d4 = idx % 96;
    float4 v = *(const float4*)(Fb + (size_t)(n0 + r) * DFEAT + d4 * 4);
    *(float4*)(frows + r * 392 + d4 * 4) = v;
  }

  const int tidy = tid >> 5;
  const int tidx = tid & 31;
  const int r0 = tidy * 2, r1 = r0 + 1;
  const float invn0 = invfb[n0 + r0];
  const float invn1 = invfb[n0 + r1];

  float v7a[KNN], v7b[KNN];
  int   i7a[KNN], i7b[KNN];
#pragma unroll
  for (int t = 0; t < KNN; ++t) { v7a[t] = -1e30f; v7b[t] = -1e30f; i7a[t] = 0; i7b[t] = 0; }
  float vmina = -1e30f, vminb = -1e30f;
  int   pmina = 0, pminb = 0;

  for (int mt = 0; mt < NPTS / 128; ++mt) {
    const int m0 = mt * 128;
    float acc0[4] = {0.f, 0.f, 0.f, 0.f};
    float acc1[4] = {0.f, 0.f, 0.f, 0.f};
    __syncthreads();                 // prior iteration done reading invm/tile
    if (tid < 128) invm[tid] = invfb[m0 + tid];
    for (int ch = 0; ch < DFEAT / 64; ++ch) {
      __syncthreads();
      // stage tile[d][m]: 128 m-rows x 16 float4 (transposed scatter writes,
      // lanes hit distinct banks: addr%32 == mloc%32, 2-way dup = free)
#pragma unroll
      for (int k = 0; k < 8; ++k) {
        int idx  = tid + k * 256;            // 0..2047
        int mloc = idx & 127, d4 = idx >> 7; // d4 0..15
        float4 v = *(const float4*)(Fb + (size_t)(m0 + mloc) * DFEAT + ch * 64 + d4 * 4);
        tileT[(d4 * 4 + 0) * 128 + mloc] = v.x;
        tileT[(d4 * 4 + 1) * 128 + mloc] = v.y;
        tileT[(d4 * 4 + 2) * 128 + mloc] = v.z;
        tileT[(d4 * 4 + 3) * 128 + mloc] = v.w;
      }
      __syncthreads();
      const float* fr0 = frows + r0 * 392 + ch * 64;
      const float* fr1 = frows + r1 * 392 + ch * 64;
#pragma unroll 4
      for (int d4 = 0; d4 < 16; ++d4) {
        float4 a0 = *(const float4*)(fr0 + d4 * 4);
        float4 a1 = *(const float4*)(fr1 + d4 * 4);
        const float* tp = tileT + d4 * 4 * 128 + tidx * 4;
        float4 t0 = *(const float4*)(tp);
        float4 t1 = *(const float4*)(tp + 128);
        float4 t2 = *(const float4*)(tp + 256);
        float4 t3 = *(const float4*)(tp + 384);
        fma4(a0, t0, t1, t2, t3, acc0);
        fma4(a1, t0, t1, t2, t3, acc1);
      }
    }
    // epilogue: scale to cosine, update top-7
#pragma unroll
    for (int j = 0; j < 4; ++j) {
      const int ml = tidx * 4 + j;
      const float im = invm[ml];
      top7_insert(acc0[j] * invn0 * im, m0 + ml, v7a, i7a, vmina, pmina);
      top7_insert(acc1[j] * invn1 * im, m0 + ml, v7b, i7b, vminb, pminb);
    }
  }

  // merge: 32 threads x 7 candidates per row -> global top-7 (overlay on tileT)
  __syncthreads();
  float* mval = tileT;                      // [16][224]
  int*   midx = (int*)(tileT + 16 * 224);   // [16][224]
#pragma unroll
  for (int t = 0; t < KNN; ++t) {
    mval[r0 * 224 + tidx * 7 + t] = v7a[t];
    midx[r0 * 224 + tidx * 7 + t] = i7a[t];
    mval[r1 * 224 + tidx * 7 + t] = v7b[t];
    midx[r1 * 224 + tidx * 7 + t] = i7b[t];
  }
  __syncthreads();
  if (tid < 16) {
    float* rv = mval + tid * 224;
    int*   ri = midx + tid * 224;
    int* outp = knn_out + (size_t)(b * NPTS + n0 + tid) * KNN;
    for (int k = 0; k < KNN; ++k) {
      float best = rv[0]; int bp = 0;
      for (int t = 1; t < 224; ++t) {
        if (rv[t] > best) { best = rv[t]; bp = t; }
      }
      outp[k] = ri[bp];
      rv[bp] = -1e30f;
    }
  }
}

// ---------------------------------------------------------------------------
// K3: code similarities -> online LSE + depth-weighted sum + knn gather
// same tiling as K2; D padded 90 -> 96 with zeros
// ---------------------------------------------------------------------------
__global__ __launch_bounds__(256, 2)
void loss_kernel(const float* __restrict__ codes, const float* __restrict__ depth,
                 const float* __restrict__ invc, const int* __restrict__ knn,
                 float* __restrict__ part_stego, float* __restrict__ part_depth) {
  __shared__ alignas(16) float crows[16 * 96];
  __shared__ alignas(16) float tileT[96 * 128];
  __shared__ float dep_m[128], invm[128];
  __shared__ float mmx[16 * 32], msm[16 * 32], mdp[16 * 32];
  __shared__ float lse_row[16], dep_row[16], dn_sh[16], invn_sh[16];
  __shared__ float sgather[112];

  const int tid = threadIdx.x;
  const int b   = blockIdx.x >> 8;
  const int n0  = (blockIdx.x & 255) * 16;
  const float* Cb    = codes + (size_t)b * NPTS * DCODE;
  const float* invcb = invc + b * NPTS;
  const float* depb  = depth + b * NPTS;

  // stage 16 c-rows zero-padded to 96
  for (int k = 0; k < 4; ++k) {
    int idx = tid + k * 256;
    if (idx < 720) {                         // 16 * 45 float2
      int r = idx / 45, p = idx % 45;
      float2 v = *(const float2*)(Cb + (size_t)(n0 + r) * DCODE + p * 2);
      crows[r * 96 + p * 2]     = v.x;
      crows[r * 96 + p * 2 + 1] = v.y;
    } else if (idx < 816) {
      int i2 = idx - 720;                    // 16 * 6 zero pads
      crows[(i2 / 6) * 96 + 90 + (i2 % 6)] = 0.f;
    }
  }
  if (tid < 16) {
    dn_sh[tid]   = depb[n0 + tid];
    invn_sh[tid] = invcb[n0 + tid];
  }
  __syncthreads();

  const int tidy = tid >> 5, tidx = tid & 31;
  const int r0 = tidy * 2, r1 = r0 + 1;
  const float invn0 = invn_sh[r0], invn1 = invn_sh[r1];
  const float dn0 = dn_sh[r0], dn1 = dn_sh[r1];

  float mx0 = -1e30f, sm0 = 0.f, mx1 = -1e30f, sm1 = 0.f;
  float dp0 = 0.f, dp1 = 0.f;

  for (int mt = 0; mt < NPTS / 128; ++mt) {
    const int m0 = mt * 128;
    float acc0[4] = {0.f, 0.f, 0.f, 0.f};
    float acc1[4] = {0.f, 0.f, 0.f, 0.f};
    __syncthreads();
    if (tid < 128) { invm[tid] = invcb[m0 + tid]; dep_m[tid] = depb[m0 + tid]; }
    for (int k = 0; k < 23; ++k) {           // 128 rows * 45 float2 = 5760
      int idx = tid + k * 256;
      if (idx < 5760) {
        int mloc = idx % 128, p = idx / 128;
        float2 v = *(const float2*)(Cb + (size_t)(m0 + mloc) * DCODE + p * 2);
        tileT[(p * 2) * 128 + mloc]     = v.x;
        tileT[(p * 2 + 1) * 128 + mloc] = v.y;
      }
    }
    for (int k = 0; k < 3; ++k) {            // zero-pad d = 90..95
      int idx = tid + k * 256;
      tileT[(90 + idx / 128) * 128 + (idx % 128)] = 0.f;
    }
    __syncthreads();
    const float* cr0 = crows + r0 * 96;
    const float* cr1 = crows + r1 * 96;
#pragma unroll 4
    for (int d4 = 0; d4 < 24; ++d4) {
      float4 a0 = *(const float4*)(cr0 + d4 * 4);
      float4 a1 = *(const float4*)(cr1 + d4 * 4);
      const float* tp = tileT + d4 * 4 * 128 + tidx * 4;
      float4 t0 = *(const float4*)(tp);
      float4 t1 = *(const float4*)(tp + 128);
      float4 t2 = *(const float4*)(tp + 256);
      float4 t3 = *(const float4*)(tp + 384);
      fma4(a0, t0, t1, t2, t3, acc0);
      fma4(a1, t0, t1, t2, t3, acc1);
    }
    // epilogue: cosine, depth term, online LSE (batch of 4)
    float l0[4], l1[4];
#pragma unroll
    for (int j = 0; j < 4; ++j) {
      const int ml = tidx * 4 + j;
      const float im = invm[ml];
      const float s0 = acc0[j] * invn0 * im;
      const float s1 = acc1[j] * invn1 * im;
      l0[j] = s0 * INV_T; l1[j] = s1 * INV_T;
      const float dm = dep_m[ml];
      const float dd0 = dn0 - dm, dd1 = dn1 - dm;
      dp0 += __expf(-2.f * dd0 * dd0) * (1.f - s0);   // sigma=0.5 -> exp(-2 dd^2)
      dp1 += __expf(-2.f * dd1 * dd1) * (1.f - s1);
    }
    {
      const float tm = fmaxf(fmaxf(l0[0], l0[1]), fmaxf(l0[2], l0[3]));
      const float nm = fmaxf(mx0, tm);
      sm0 = sm0 * __expf(mx0 - nm) + __expf(l0[0] - nm) + __expf(l0[1] - nm)
          + __expf(l0[2] - nm) + __expf(l0[3] - nm);
      mx0 = nm;
    }
    {
      const float tm = fmaxf(fmaxf(l1[0], l1[1]), fmaxf(l1[2], l1[3]));
      const float nm = fmaxf(mx1, tm);
      sm1 = sm1 * __expf(mx1 - nm) + __expf(l1[0] - nm) + __expf(l1[1] - nm)
          + __expf(l1[2] - nm) + __expf(l1[3] - nm);
      mx1 = nm;
    }
  }

  // per-row merge of 32 partial (max,sum) pairs and depth partials
  mmx[r0 * 32 + tidx] = mx0; msm[r0 * 32 + tidx] = sm0; mdp[r0 * 32 + tidx] = dp0;
  mmx[r1 * 32 + tidx] = mx1; msm[r1 * 32 + tidx] = sm1; mdp[r1 * 32 + tidx] = dp1;
  __syncthreads();
  if (tid < 16) {
    float M = -1e30f;
    for (int i = 0; i < 32; ++i) M = fmaxf(M, mmx[tid * 32 + i]);
    float S = 0.f, D = 0.f;
    for (int i = 0; i < 32; ++i) {
      S += msm[tid * 32 + i] * __expf(mmx[tid * 32 + i] - M);
      D += mdp[tid * 32 + i];
    }
    lse_row[tid] = M + __logf(S);
    dep_row[tid] = D;
  }
  __syncthreads();
  // stego gather: one thread per (row, k): -logp = lse - s/T
  if (tid < 112) {
    const int r = tid / 7, k = tid % 7;
    const int m = knn[(size_t)(b * NPTS + n0 + r) * KNN + k];
    const float* cm = Cb + (size_t)m * DCODE;
    const float* cn = crows + r * 96;
    float dot = 0.f;
    for (int d = 0; d < DCODE; ++d) dot += cn[d] * cm[d];
    const float s = dot * invn_sh[r] * invcb[m];
    sgather[tid] = lse_row[r] - s * INV_T;
  }
  __syncthreads();
  if (tid == 0) {
    float ss = 0.f;
    for (int i = 0; i < 112; ++i) ss += sgather[i];
    float dsum = 0.f;
    for (int i = 0; i < 16; ++i) dsum += dep_row[i];
    part_stego[blockIdx.x] = ss;
    part_depth[blockIdx.x] = dsum;
  }
}

// ---------------------------------------------------------------------------
// K4: final reduction -> (l_stego, l_depthg, total)
// ---------------------------------------------------------------------------
__global__ void finalize_kernel(const float* __restrict__ ps,
                                const float* __restrict__ pd,
                                float* __restrict__ out) {
  __shared__ float r1[256], r2[256];
  const int tid = threadIdx.x;
  float a = 0.f, d = 0.f;
  for (int i = tid; i < 512; i += 256) { a += ps[i]; d += pd[i]; }
  r1[tid] = a; r2[tid] = d;
  __syncthreads();
  for (int s = 128; s > 0; s >>= 1) {
    if (tid < s) { r1[tid] += r1[tid + s]; r2[tid] += r2[tid + s]; }
    __syncthreads();
  }
  if (tid == 0) {
    const float l_stego = r1[0] / (float)(BATCH * NPTS * KNN);
    const float l_dep   = r2[0] / ((float)BATCH * (float)NPTS * (float)NPTS);
    out[0] = l_stego;
    out[1] = l_dep;
    out[2] = l_stego + LAMBDA * l_dep;
  }
}

// ---------------------------------------------------------------------------
extern "C" void kernel_launch(void* const* d_in, const int* in_sizes, int n_in,
                              void* d_out, int out_size, void* d_ws, size_t ws_size,
                              hipStream_t stream) {
  (void)in_sizes; (void)n_in; (void)out_size; (void)ws_size;
  const float* codes = (const float*)d_in[0];   // (B,N,90)
  const float* feats = (const float*)d_in[1];   // (B,N,384)
  const float* depth = (const float*)d_in[2];   // (B,N)
  float* out = (float*)d_out;                   // 3 floats

  float* wsf = (float*)d_ws;
  float* invc = wsf;                 // 8192
  float* invf = wsf + 8192;          // 8192
  float* part_s = wsf + 16384;       // 512
  float* part_d = wsf + 16896;       // 512
  int*   knn    = (int*)(wsf + 17408); // B*N*7 = 57344 ints

  norms_kernel<<<BATCH * NPTS, 256, 0, stream>>>(codes, feats, invc, invf);
  knn_kernel<<<512, 256, 0, stream>>>(feats, invf, knn);
  loss_kernel<<<512, 256, 0, stream>>>(codes, depth, invc, knn, part_s, part_d);
  finalize_kernel<<<1, 256, 0, stream>>>(part_s, part_d, out);
}

// Round 3
// 326.350 us; speedup vs baseline: 3.4905x; 3.4905x over previous
//
#include <hip/hip_runtime.h>
#include <math.h>

#define NPTS 4096

typedef __attribute__((ext_vector_type(8))) short bf16x8;
typedef __attribute__((ext_vector_type(16))) float f32x16;

__device__ __forceinline__ f32x16 zero16() {
  f32x16 z;
#pragma unroll
  for (int i = 0; i < 16; ++i) z[i] = 0.f;
  return z;
}

// top-7 insertion, fully static register indexing (rule #20)
__device__ __forceinline__ void top7_insert(float v, int i, float* v7, int* i7,
                                            float& vmin, int& pmin) {
  if (v > vmin) {
#pragma unroll
    for (int t = 0; t < 7; ++t)
      if (t == pmin) { v7[t] = v; i7[t] = i; }
    vmin = v7[0]; pmin = 0;
#pragma unroll
    for (int t = 1; t < 7; ++t)
      if (v7[t] < vmin) { vmin = v7[t]; pmin = t; }
  }
}

__device__ __forceinline__ unsigned bf16pack(float a, float b) {
  unsigned ua = __float_as_uint(a); ua = (ua + 0x7FFFu + ((ua >> 16) & 1u)) >> 16;
  unsigned ub = __float_as_uint(b); ub = (ub + 0x7FFFu + ((ub >> 16) & 1u)) >> 16;
  return ua | (ub << 16);
}

// ---------------------------------------------------------------------------
// K1: normalize rows, cast to bf16. Fn: (B,N,384). Cn: (B,N,96) zero-padded.
// Also writes invc (fp32 inverse code norms) for the fp32 positive gather.
// ---------------------------------------------------------------------------
__global__ __launch_bounds__(64) void norm_cast(const float* __restrict__ codes,
                                                const float* __restrict__ feats,
                                                unsigned short* __restrict__ Fn,
                                                unsigned short* __restrict__ Cn,
                                                float* __restrict__ invc) {
  const int row = blockIdx.x;            // 0 .. 8191
  const int lane = threadIdx.x;
  // features: 384 floats
  const float* f = feats + (size_t)row * 384;
  float2 v[3];
  float ss = 0.f;
#pragma unroll
  for (int j = 0; j < 3; ++j) {
    v[j] = *(const float2*)(f + j * 128 + lane * 2);
    ss = fmaf(v[j].x, v[j].x, ss);
    ss = fmaf(v[j].y, v[j].y, ss);
  }
#pragma unroll
  for (int m = 1; m <= 32; m <<= 1) ss += __shfl_xor(ss, m, 64);
  const float inv = rsqrtf(ss + 1e-8f);
  unsigned* Fo = (unsigned*)(Fn + (size_t)row * 384);
#pragma unroll
  for (int j = 0; j < 3; ++j)
    Fo[j * 64 + lane] = bf16pack(v[j].x * inv, v[j].y * inv);
  // codes: 90 floats -> 96 bf16 (zero-padded)
  const float* c = codes + (size_t)row * 90;
  float2 cv = make_float2(0.f, 0.f);
  if (lane < 45) cv = *(const float2*)(c + lane * 2);
  float cs = fmaf(cv.x, cv.x, cv.y * cv.y);
#pragma unroll
  for (int m = 1; m <= 32; m <<= 1) cs += __shfl_xor(cs, m, 64);
  const float cinv = rsqrtf(cs + 1e-8f);
  const unsigned pc = (lane < 45) ? bf16pack(cv.x * cinv, cv.y * cinv) : 0u;
  if (lane < 48) ((unsigned*)(Cn + (size_t)row * 96))[lane] = pc;
  if (lane == 0) invc[row] = cinv;
}

// ---------------------------------------------------------------------------
// K2: feature similarities via 32x32x16 bf16 MFMA (swapped: D[m][q]) + top-7.
// One wave per 32 q-columns, sweeping all 4096 m. Self index is FORCED into
// the final set (reference top_k provably always contains self).
// ---------------------------------------------------------------------------
__global__ __launch_bounds__(64, 1) void knn_mfma(const unsigned short* __restrict__ Fn,
                                                  int* __restrict__ knn_out) {
  const int g = blockIdx.x;              // 0..255
  const int b = g >> 7;
  const int q0 = (g & 127) * 32;
  const int lane = threadIdx.x;
  const int lo = lane & 31, hi = lane >> 5, hi4 = (lane >> 5) * 4;
  const unsigned short* Fb = Fn + (size_t)b * NPTS * 384;

  bf16x8 bfr[24];
  {
    const unsigned short* qr = Fb + (size_t)(q0 + lo) * 384 + hi * 8;
#pragma unroll
    for (int t = 0; t < 24; ++t) bfr[t] = *(const bf16x8*)(qr + t * 16);
  }
  float v7[7]; int i7[7]; float vmin = -1e30f; int pmin = 0;
#pragma unroll
  for (int t = 0; t < 7; ++t) { v7[t] = -1e30f; i7[t] = 0; }

  const unsigned short* ar0 = Fb + (size_t)lo * 384 + hi * 8;
  bf16x8 a0[24], a1[24];
#pragma unroll
  for (int t = 0; t < 24; ++t) a0[t] = *(const bf16x8*)(ar0 + t * 16);

#define PROC(A, MT)                                                            \
  {                                                                            \
    f32x16 acc = zero16();                                                     \
    _Pragma("unroll")                                                          \
    for (int t = 0; t < 24; ++t)                                               \
      acc = __builtin_amdgcn_mfma_f32_32x32x16_bf16(A[t], bfr[t], acc, 0, 0, 0); \
    const int mb = (MT) * 32 + hi4;                                            \
    _Pragma("unroll")                                                          \
    for (int r = 0; r < 16; ++r) {                                             \
      const int m = mb + (r & 3) + 8 * (r >> 2);                               \
      top7_insert(acc[r], m, v7, i7, vmin, pmin);                              \
    }                                                                          \
  }

  for (int mt = 0; mt < 128; mt += 2) {
    {
      const unsigned short* ar = ar0 + (size_t)(mt + 1) * 32 * 384;
#pragma unroll
      for (int t = 0; t < 24; ++t) a1[t] = *(const bf16x8*)(ar + t * 16);
    }
    PROC(a0, mt)
    if (mt + 2 < 128) {
      const unsigned short* ar = ar0 + (size_t)(mt + 2) * 32 * 384;
#pragma unroll
      for (int t = 0; t < 24; ++t) a0[t] = *(const bf16x8*)(ar + t * 16);
    }
    PROC(a1, mt + 1)
  }
#undef PROC

  // merge lane pairs (lane, lane^32) covering the same q-column
  float nv[7]; int ni[7]; float nvm = -1e30f; int npm = 0;
#pragma unroll
  for (int t = 0; t < 7; ++t) { nv[t] = -1e30f; ni[t] = 0; }
#pragma unroll
  for (int t = 0; t < 7; ++t) {
    float ov = __shfl_xor(v7[t], 32, 64);
    int   oi = __shfl_xor(i7[t], 32, 64);
    top7_insert(v7[t], i7[t], nv, ni, nvm, npm);
    top7_insert(ov, oi, nv, ni, nvm, npm);
  }
  // FORCE self: reference knn always contains q (self-sim = 1 is the max).
  const int q = q0 + (lane & 31);
  bool has = false;
#pragma unroll
  for (int t = 0; t < 7; ++t) has = has || (ni[t] == q);
  if (!has) {
    float mn = nv[0]; int mp = 0;
#pragma unroll
    for (int t = 1; t < 7; ++t)
      if (nv[t] < mn) { mn = nv[t]; mp = t; }
#pragma unroll
    for (int t = 0; t < 7; ++t)
      if (t == mp) ni[t] = q;
  }
  if (lane < 32) {
    int* o = knn_out + ((size_t)b * NPTS + q0 + lane) * 7;
#pragma unroll
    for (int t = 0; t < 7; ++t) o[t] = ni[t];
  }
}

// ---------------------------------------------------------------------------
// K3: code similarities -> fixed-max LSE (max logit == 10 from self-sim) +
// depth-Gaussian weighted sum. Same skeleton as K2, K=96.
// ---------------------------------------------------------------------------
__global__ __launch_bounds__(64, 1) void lse_depth(const unsigned short* __restrict__ Cn,
                                                   const float* __restrict__ depth,
                                                   float* __restrict__ lse_out,
                                                   float* __restrict__ dpart) {
  const int g = blockIdx.x;
  const int b = g >> 7;
  const int q0 = (g & 127) * 32;
  const int lane = threadIdx.x;
  const int lo = lane & 31, hi = lane >> 5, hi4 = (lane >> 5) * 4;
  const unsigned short* Cb = Cn + (size_t)b * NPTS * 96;
  const float* db = depth + b * NPTS;

  bf16x8 bfr[6];
  {
    const unsigned short* qr = Cb + (size_t)(q0 + lo) * 96 + hi * 8;
#pragma unroll
    for (int t = 0; t < 6; ++t) bfr[t] = *(const bf16x8*)(qr + t * 16);
  }
  const float dq = db[q0 + lo];
  float slse = 0.f, sdep = 0.f;

  const unsigned short* ar0 = Cb + (size_t)lo * 96 + hi * 8;
  bf16x8 a0[6], a1[6];
#pragma unroll
  for (int t = 0; t < 6; ++t) a0[t] = *(const bf16x8*)(ar0 + t * 16);

#define PROC3(A, MT)                                                           \
  {                                                                            \
    f32x16 acc = zero16();                                                     \
    _Pragma("unroll")                                                          \
    for (int t = 0; t < 6; ++t)                                                \
      acc = __builtin_amdgcn_mfma_f32_32x32x16_bf16(A[t], bfr[t], acc, 0, 0, 0); \
    float dvv[16];                                                             \
    _Pragma("unroll")                                                          \
    for (int k = 0; k < 4; ++k) {                                              \
      float4 dv = *(const float4*)(db + (MT) * 32 + hi4 + 8 * k);              \
      dvv[k * 4 + 0] = dv.x; dvv[k * 4 + 1] = dv.y;                            \
      dvv[k * 4 + 2] = dv.z; dvv[k * 4 + 3] = dv.w;                            \
    }                                                                          \
    _Pragma("unroll")                                                          \
    for (int r = 0; r < 16; ++r) {                                             \
      const float s = acc[r];                                                  \
      const float dd = dq - dvv[r];                                            \
      sdep += __expf(-2.f * dd * dd) * (1.f - s);                              \
      slse += __expf(fmaf(s, 10.f, -10.f));                                    \
    }                                                                          \
  }

  for (int mt = 0; mt < 128; mt += 2) {
    {
      const unsigned short* ar = ar0 + (size_t)(mt + 1) * 32 * 96;
#pragma unroll
      for (int t = 0; t < 6; ++t) a1[t] = *(const bf16x8*)(ar + t * 16);
    }
    PROC3(a0, mt)
    if (mt + 2 < 128) {
      const unsigned short* ar = ar0 + (size_t)(mt + 2) * 32 * 96;
#pragma unroll
      for (int t = 0; t < 6; ++t) a0[t] = *(const bf16x8*)(ar + t * 16);
    }
    PROC3(a1, mt + 1)
  }
#undef PROC3

  slse += __shfl_xor(slse, 32, 64);
  if (lane < 32) lse_out[(size_t)b * NPTS + q0 + lane] = 10.f + __logf(slse);
#pragma unroll
  for (int m = 1; m <= 32; m <<= 1) sdep += __shfl_xor(sdep, m, 64);
  if (lane == 0) dpart[g] = sdep;
}

// ---------------------------------------------------------------------------
// K4: positive-pair code similarity in FP32 from raw codes. One wave per row.
// ---------------------------------------------------------------------------
__global__ __launch_bounds__(64) void gather_pos(const float* __restrict__ codes,
                                                 const float* __restrict__ invc,
                                                 const int* __restrict__ knn,
                                                 float* __restrict__ gpart) {
  const int n = blockIdx.x;              // 0..8191 (global row)
  const int b = n >> 12;
  const int lane = threadIdx.x;
  const float* cn = codes + (size_t)n * 90;
  float2 a = make_float2(0.f, 0.f);
  if (lane < 45) a = *(const float2*)(cn + lane * 2);
  const float inva = invc[n];
  float ssum = 0.f;
  for (int k = 0; k < 7; ++k) {
    const int m = knn[(size_t)n * 7 + k];
    const float* cm = codes + ((size_t)(b << 12) + m) * 90;
    float2 bb = make_float2(0.f, 0.f);
    if (lane < 45) bb = *(const float2*)(cm + lane * 2);
    float p = fmaf(a.x, bb.x, a.y * bb.y);
#pragma unroll
    for (int w = 1; w <= 32; w <<= 1) p += __shfl_xor(p, w, 64);
    ssum += p * inva * invc[(b << 12) + m];
  }
  if (lane == 0) gpart[n] = ssum;
}

// ---------------------------------------------------------------------------
// K5: finalize -> (l_stego, l_depthg, total)
// ---------------------------------------------------------------------------
__global__ __launch_bounds__(256) void finalize(const float* __restrict__ lse,
                                                const float* __restrict__ gpart,
                                                const float* __restrict__ dpart,
                                                float* __restrict__ out) {
  const int tid = threadIdx.x;
  float s1 = 0.f, s2 = 0.f;
  for (int i = tid; i < 2 * NPTS; i += 256) { s1 += lse[i]; s2 += gpart[i]; }
  float s3 = dpart[tid];
  __shared__ float r1[256], r2[256], r3[256];
  r1[tid] = s1; r2[tid] = s2; r3[tid] = s3;
  __syncthreads();
  for (int s = 128; s > 0; s >>= 1) {
    if (tid < s) { r1[tid] += r1[tid + s]; r2[tid] += r2[tid + s]; r3[tid] += r3[tid + s]; }
    __syncthreads();
  }
  if (tid == 0) {
    const float l_st = (7.f * r1[0] - 10.f * r2[0]) / 57344.f;
    const float l_dp = r3[0] / 33554432.f;
    out[0] = l_st;
    out[1] = l_dp;
    out[2] = l_st + 0.3f * l_dp;
  }
}

// ---------------------------------------------------------------------------
extern "C" void kernel_launch(void* const* d_in, const int* in_sizes, int n_in,
                              void* d_out, int out_size, void* d_ws, size_t ws_size,
                              hipStream_t stream) {
  (void)in_sizes; (void)n_in; (void)out_size; (void)ws_size;
  const float* codes = (const float*)d_in[0];   // (B,N,90)
  const float* feats = (const float*)d_in[1];   // (B,N,384)
  const float* depth = (const float*)d_in[2];   // (B,N)
  float* out = (float*)d_out;

  // Defensive layout: small critical buffers first.
  char* ws = (char*)d_ws;
  float* invc  = (float*)ws;                         // 32768 B  @ 0
  float* lse   = (float*)(ws + 32768);               // 32768 B
  float* dpart = (float*)(ws + 65536);               // 1024 B
  float* gpart = (float*)(ws + 66560);               // 32768 B
  int*   knn   = (int*)(ws + 99328);                 // 229376 B
  unsigned short* Cn = (unsigned short*)(ws + 328704);   // 1572864 B
  unsigned short* Fn = (unsigned short*)(ws + 1901568);  // 6291456 B (end 8193024)

  norm_cast<<<2 * NPTS, 64, 0, stream>>>(codes, feats, Fn, Cn, invc);
  knn_mfma<<<256, 64, 0, stream>>>(Fn, knn);
  lse_depth<<<256, 64, 0, stream>>>(Cn, depth, lse, dpart);
  gather_pos<<<2 * NPTS, 64, 0, stream>>>(codes, invc, knn, gpart);
  finalize<<<1, 256, 0, stream>>>(lse, gpart, dpart, out);
}

// Round 4
// 235.777 us; speedup vs baseline: 4.8313x; 1.3841x over previous
//
#include <hip/hip_runtime.h>
#include <math.h>

#define NPTS 4096

typedef __attribute__((ext_vector_type(8))) short bf16x8;
typedef __attribute__((ext_vector_type(16))) float f32x16;

__device__ __forceinline__ f32x16 zero16() {
  f32x16 z;
#pragma unroll
  for (int i = 0; i < 16; ++i) z[i] = 0.f;
  return z;
}

// top-7 insertion, fully static register indexing (rule #20)
__device__ __forceinline__ void top7_insert(float v, int i, float* v7, int* i7,
                                            float& vmin, int& pmin) {
  if (v > vmin) {
#pragma unroll
    for (int t = 0; t < 7; ++t)
      if (t == pmin) { v7[t] = v; i7[t] = i; }
    vmin = v7[0]; pmin = 0;
#pragma unroll
    for (int t = 1; t < 7; ++t)
      if (v7[t] < vmin) { vmin = v7[t]; pmin = t; }
  }
}

__device__ __forceinline__ unsigned bf16pack(float a, float b) {
  unsigned ua = __float_as_uint(a); ua = (ua + 0x7FFFu + ((ua >> 16) & 1u)) >> 16;
  unsigned ub = __float_as_uint(b); ub = (ub + 0x7FFFu + ((ub >> 16) & 1u)) >> 16;
  return ua | (ub << 16);
}

// ---------------------------------------------------------------------------
// K1: normalize rows, cast to bf16. Fn: (B,N,384). Cn: (B,N,96) zero-padded.
// Also writes invc (fp32 inverse code norms) for the fp32 positive gather.
// ---------------------------------------------------------------------------
__global__ __launch_bounds__(64) void norm_cast(const float* __restrict__ codes,
                                                const float* __restrict__ feats,
                                                unsigned short* __restrict__ Fn,
                                                unsigned short* __restrict__ Cn,
                                                float* __restrict__ invc) {
  const int row = blockIdx.x;            // 0 .. 8191
  const int lane = threadIdx.x;
  const float* f = feats + (size_t)row * 384;
  float2 v[3];
  float ss = 0.f;
#pragma unroll
  for (int j = 0; j < 3; ++j) {
    v[j] = *(const float2*)(f + j * 128 + lane * 2);
    ss = fmaf(v[j].x, v[j].x, ss);
    ss = fmaf(v[j].y, v[j].y, ss);
  }
#pragma unroll
  for (int m = 1; m <= 32; m <<= 1) ss += __shfl_xor(ss, m, 64);
  const float inv = rsqrtf(ss + 1e-8f);
  unsigned* Fo = (unsigned*)(Fn + (size_t)row * 384);
#pragma unroll
  for (int j = 0; j < 3; ++j)
    Fo[j * 64 + lane] = bf16pack(v[j].x * inv, v[j].y * inv);
  const float* c = codes + (size_t)row * 90;
  float2 cv = make_float2(0.f, 0.f);
  if (lane < 45) cv = *(const float2*)(c + lane * 2);
  float cs = fmaf(cv.x, cv.x, cv.y * cv.y);
#pragma unroll
  for (int m = 1; m <= 32; m <<= 1) cs += __shfl_xor(cs, m, 64);
  const float cinv = rsqrtf(cs + 1e-8f);
  const unsigned pc = (lane < 45) ? bf16pack(cv.x * cinv, cv.y * cinv) : 0u;
  if (lane < 48) ((unsigned*)(Cn + (size_t)row * 96))[lane] = pc;
  if (lane == 0) invc[row] = cinv;
}

// ---------------------------------------------------------------------------
// K2: feature similarities via 32x32x16 bf16 MFMA (swapped: D[m][q]) + top-7.
// 8 waves/block; wave w sweeps m in [w*512,(w+1)*512). Candidates merged in
// LDS; self index FORCED into the final set (reference top_k always has self).
// ---------------------------------------------------------------------------
__global__ __launch_bounds__(512, 2) void knn_mfma(const unsigned short* __restrict__ Fn,
                                                   int* __restrict__ knn_out) {
  __shared__ float cval[8][32][7];
  __shared__ int   cidx[8][32][7];
  const int g = blockIdx.x;              // 0..255
  const int b = g >> 7;
  const int q0 = (g & 127) * 32;
  const int tid = threadIdx.x;
  const int w = tid >> 6;
  const int lane = tid & 63;
  const int lo = lane & 31, hi = lane >> 5, hi4 = (lane >> 5) * 4;
  const unsigned short* Fb = Fn + (size_t)b * NPTS * 384;

  bf16x8 bfr[24];
  {
    const unsigned short* qr = Fb + (size_t)(q0 + lo) * 384 + hi * 8;
#pragma unroll
    for (int t = 0; t < 24; ++t) bfr[t] = *(const bf16x8*)(qr + t * 16);
  }
  float v7[7]; int i7[7]; float vmin = -1e30f; int pmin = 0;
#pragma unroll
  for (int t = 0; t < 7; ++t) { v7[t] = -1e30f; i7[t] = 0; }

  const int mbase = w * 512;             // this wave's m-range
  const unsigned short* ar0 = Fb + (size_t)(mbase + lo) * 384 + hi * 8;
  bf16x8 a0[24], a1[24];
#pragma unroll
  for (int t = 0; t < 24; ++t) a0[t] = *(const bf16x8*)(ar0 + t * 16);

#define PROC(A, MT)                                                            \
  {                                                                            \
    f32x16 acc = zero16();                                                     \
    _Pragma("unroll")                                                          \
    for (int t = 0; t < 24; ++t)                                               \
      acc = __builtin_amdgcn_mfma_f32_32x32x16_bf16(A[t], bfr[t], acc, 0, 0, 0); \
    const int mb = mbase + (MT) * 32 + hi4;                                    \
    _Pragma("unroll")                                                          \
    for (int r = 0; r < 16; ++r) {                                             \
      const int m = mb + (r & 3) + 8 * (r >> 2);                               \
      top7_insert(acc[r], m, v7, i7, vmin, pmin);                              \
    }                                                                          \
  }

  for (int mt = 0; mt < 16; mt += 2) {
    {
      const unsigned short* ar = ar0 + (size_t)(mt + 1) * 32 * 384;
#pragma unroll
      for (int t = 0; t < 24; ++t) a1[t] = *(const bf16x8*)(ar + t * 16);
    }
    PROC(a0, mt)
    if (mt + 2 < 16) {
      const unsigned short* ar = ar0 + (size_t)(mt + 2) * 32 * 384;
#pragma unroll
      for (int t = 0; t < 24; ++t) a0[t] = *(const bf16x8*)(ar + t * 16);
    }
    PROC(a1, mt + 1)
  }
#undef PROC

  // merge lane pairs (lane, lane^32) covering the same q-column
  float nv[7]; int ni[7]; float nvm = -1e30f; int npm = 0;
#pragma unroll
  for (int t = 0; t < 7; ++t) { nv[t] = -1e30f; ni[t] = 0; }
#pragma unroll
  for (int t = 0; t < 7; ++t) {
    float ov = __shfl_xor(v7[t], 32, 64);
    int   oi = __shfl_xor(i7[t], 32, 64);
    top7_insert(v7[t], i7[t], nv, ni, nvm, npm);
    top7_insert(ov, oi, nv, ni, nvm, npm);
  }
  if (lane < 32) {
#pragma unroll
    for (int t = 0; t < 7; ++t) { cval[w][lo][t] = nv[t]; cidx[w][lo][t] = ni[t]; }
  }
  __syncthreads();

  // final merge: 32 threads, one q each, scan 8 waves x 7 candidates
  if (tid < 32) {
    float fv[7]; int fi[7]; float fvm = -1e30f; int fpm = 0;
#pragma unroll
    for (int t = 0; t < 7; ++t) { fv[t] = -1e30f; fi[t] = 0; }
    for (int w2 = 0; w2 < 8; ++w2)
#pragma unroll
      for (int t = 0; t < 7; ++t)
        top7_insert(cval[w2][tid][t], cidx[w2][tid][t], fv, fi, fvm, fpm);
    // FORCE self (self-sim = 1 is always the reference max)
    const int q = q0 + tid;
    bool has = false;
#pragma unroll
    for (int t = 0; t < 7; ++t) has = has || (fi[t] == q);
    if (!has) {
      float mn = fv[0]; int mp = 0;
#pragma unroll
      for (int t = 1; t < 7; ++t)
        if (fv[t] < mn) { mn = fv[t]; mp = t; }
#pragma unroll
      for (int t = 0; t < 7; ++t)
        if (t == mp) fi[t] = q;
    }
    int* o = knn_out + ((size_t)b * NPTS + q) * 7;
#pragma unroll
    for (int t = 0; t < 7; ++t) o[t] = fi[t];
  }
}

// ---------------------------------------------------------------------------
// K3: code similarities -> fixed-max LSE (max logit == 10 from self-sim) +
// depth-Gaussian weighted sum. 8-wave m-split, LDS partial merge.
// ---------------------------------------------------------------------------
__global__ __launch_bounds__(512, 2) void lse_depth(const unsigned short* __restrict__ Cn,
                                                    const float* __restrict__ depth,
                                                    float* __restrict__ lse_out,
                                                    float* __restrict__ dpart) {
  __shared__ float lsep[8][32];
  __shared__ float depp[8];
  const int g = blockIdx.x;
  const int b = g >> 7;
  const int q0 = (g & 127) * 32;
  const int tid = threadIdx.x;
  const int w = tid >> 6;
  const int lane = tid & 63;
  const int lo = lane & 31, hi = lane >> 5, hi4 = (lane >> 5) * 4;
  const unsigned short* Cb = Cn + (size_t)b * NPTS * 96;
  const float* db = depth + b * NPTS;

  bf16x8 bfr[6];
  {
    const unsigned short* qr = Cb + (size_t)(q0 + lo) * 96 + hi * 8;
#pragma unroll
    for (int t = 0; t < 6; ++t) bfr[t] = *(const bf16x8*)(qr + t * 16);
  }
  const float dq = db[q0 + lo];
  float slse = 0.f, sdep = 0.f;

  const int mbase = w * 512;
  const unsigned short* ar0 = Cb + (size_t)(mbase + lo) * 96 + hi * 8;
  bf16x8 a0[6], a1[6];
#pragma unroll
  for (int t = 0; t < 6; ++t) a0[t] = *(const bf16x8*)(ar0 + t * 16);

#define PROC3(A, MT)                                                           \
  {                                                                            \
    f32x16 acc = zero16();                                                     \
    _Pragma("unroll")                                                          \
    for (int t = 0; t < 6; ++t)                                                \
      acc = __builtin_amdgcn_mfma_f32_32x32x16_bf16(A[t], bfr[t], acc, 0, 0, 0); \
    float dvv[16];                                                             \
    _Pragma("unroll")                                                          \
    for (int k = 0; k < 4; ++k) {                                              \
      float4 dv = *(const float4*)(db + mbase + (MT) * 32 + hi4 + 8 * k);      \
      dvv[k * 4 + 0] = dv.x; dvv[k * 4 + 1] = dv.y;                            \
      dvv[k * 4 + 2] = dv.z; dvv[k * 4 + 3] = dv.w;                            \
    }                                                                          \
    _Pragma("unroll")                                                          \
    for (int r = 0; r < 16; ++r) {                                             \
      const float s = acc[r];                                                  \
      const float dd = dq - dvv[r];                                            \
      sdep += __expf(-2.f * dd * dd) * (1.f - s);                              \
      slse += __expf(fmaf(s, 10.f, -10.f));                                    \
    }                                                                          \
  }

  for (int mt = 0; mt < 16; mt += 2) {
    {
      const unsigned short* ar = ar0 + (size_t)(mt + 1) * 32 * 96;
#pragma unroll
      for (int t = 0; t < 6; ++t) a1[t] = *(const bf16x8*)(ar + t * 16);
    }
    PROC3(a0, mt)
    if (mt + 2 < 16) {
      const unsigned short* ar = ar0 + (size_t)(mt + 2) * 32 * 96;
#pragma unroll
      for (int t = 0; t < 6; ++t) a0[t] = *(const bf16x8*)(ar + t * 16);
    }
    PROC3(a1, mt + 1)
  }
#undef PROC3

  slse += __shfl_xor(slse, 32, 64);
  if (lane < 32) lsep[w][lo] = slse;
#pragma unroll
  for (int m = 1; m <= 32; m <<= 1) sdep += __shfl_xor(sdep, m, 64);
  if (lane == 0) depp[w] = sdep;
  __syncthreads();
  if (tid < 32) {
    float tot = 0.f;
#pragma unroll
    for (int w2 = 0; w2 < 8; ++w2) tot += lsep[w2][tid];
    lse_out[(size_t)b * NPTS + q0 + tid] = 10.f + __logf(tot);
  }
  if (tid == 32) {
    float d = 0.f;
#pragma unroll
    for (int w2 = 0; w2 < 8; ++w2) d += depp[w2];
    dpart[g] = d;
  }
}

// ---------------------------------------------------------------------------
// K4: positive-pair code similarity in FP32 from raw codes. One wave per row.
// ---------------------------------------------------------------------------
__global__ __launch_bounds__(64) void gather_pos(const float* __restrict__ codes,
                                                 const float* __restrict__ invc,
                                                 const int* __restrict__ knn,
                                                 float* __restrict__ gpart) {
  const int n = blockIdx.x;              // 0..8191 (global row)
  const int b = n >> 12;
  const int lane = threadIdx.x;
  const float* cn = codes + (size_t)n * 90;
  float2 a = make_float2(0.f, 0.f);
  if (lane < 45) a = *(const float2*)(cn + lane * 2);
  const float inva = invc[n];
  float ssum = 0.f;
  for (int k = 0; k < 7; ++k) {
    const int m = knn[(size_t)n * 7 + k];
    const float* cm = codes + ((size_t)(b << 12) + m) * 90;
    float2 bb = make_float2(0.f, 0.f);
    if (lane < 45) bb = *(const float2*)(cm + lane * 2);
    float p = fmaf(a.x, bb.x, a.y * bb.y);
#pragma unroll
    for (int w = 1; w <= 32; w <<= 1) p += __shfl_xor(p, w, 64);
    ssum += p * inva * invc[(b << 12) + m];
  }
  if (lane == 0) gpart[n] = ssum;
}

// ---------------------------------------------------------------------------
// K5: finalize -> (l_stego, l_depthg, total)
// ---------------------------------------------------------------------------
__global__ __launch_bounds__(256) void finalize(const float* __restrict__ lse,
                                                const float* __restrict__ gpart,
                                                const float* __restrict__ dpart,
                                                float* __restrict__ out) {
  const int tid = threadIdx.x;
  float s1 = 0.f, s2 = 0.f;
  for (int i = tid; i < 2 * NPTS; i += 256) { s1 += lse[i]; s2 += gpart[i]; }
  float s3 = dpart[tid];
  __shared__ float r1[256], r2[256], r3[256];
  r1[tid] = s1; r2[tid] = s2; r3[tid] = s3;
  __syncthreads();
  for (int s = 128; s > 0; s >>= 1) {
    if (tid < s) { r1[tid] += r1[tid + s]; r2[tid] += r2[tid + s]; r3[tid] += r3[tid + s]; }
    __syncthreads();
  }
  if (tid == 0) {
    const float l_st = (7.f * r1[0] - 10.f * r2[0]) / 57344.f;
    const float l_dp = r3[0] / 33554432.f;
    out[0] = l_st;
    out[1] = l_dp;
    out[2] = l_st + 0.3f * l_dp;
  }
}

// ---------------------------------------------------------------------------
extern "C" void kernel_launch(void* const* d_in, const int* in_sizes, int n_in,
                              void* d_out, int out_size, void* d_ws, size_t ws_size,
                              hipStream_t stream) {
  (void)in_sizes; (void)n_in; (void)out_size; (void)ws_size;
  const float* codes = (const float*)d_in[0];   // (B,N,90)
  const float* feats = (const float*)d_in[1];   // (B,N,384)
  const float* depth = (const float*)d_in[2];   // (B,N)
  float* out = (float*)d_out;

  char* ws = (char*)d_ws;
  float* invc  = (float*)ws;                         // 32768 B  @ 0
  float* lse   = (float*)(ws + 32768);               // 32768 B
  float* dpart = (float*)(ws + 65536);               // 1024 B
  float* gpart = (float*)(ws + 66560);               // 32768 B
  int*   knn   = (int*)(ws + 99328);                 // 229376 B
  unsigned short* Cn = (unsigned short*)(ws + 328704);   // 1572864 B
  unsigned short* Fn = (unsigned short*)(ws + 1901568);  // 6291456 B (end 8193024)

  norm_cast<<<2 * NPTS, 64, 0, stream>>>(codes, feats, Fn, Cn, invc);
  knn_mfma<<<256, 512, 0, stream>>>(Fn, knn);
  lse_depth<<<256, 512, 0, stream>>>(Cn, depth, lse, dpart);
  gather_pos<<<2 * NPTS, 64, 0, stream>>>(codes, invc, knn, gpart);
  finalize<<<1, 256, 0, stream>>>(lse, gpart, dpart, out);
}

// Round 5
// 225.203 us; speedup vs baseline: 5.0582x; 1.0470x over previous
//
#include <hip/hip_runtime.h>
#include <math.h>

#define NPTS 4096

typedef __attribute__((ext_vector_type(8))) short bf16x8;
typedef __attribute__((ext_vector_type(16))) float f32x16;

__device__ __forceinline__ f32x16 zero16() {
  f32x16 z;
#pragma unroll
  for (int i = 0; i < 16; ++i) z[i] = 0.f;
  return z;
}

// top-7 insertion, fully static register indexing (rule #20)
__device__ __forceinline__ void top7_insert(float v, int i, float* v7, int* i7,
                                            float& vmin, int& pmin) {
  if (v > vmin) {
#pragma unroll
    for (int t = 0; t < 7; ++t)
      if (t == pmin) { v7[t] = v; i7[t] = i; }
    vmin = v7[0]; pmin = 0;
#pragma unroll
    for (int t = 1; t < 7; ++t)
      if (v7[t] < vmin) { vmin = v7[t]; pmin = t; }
  }
}

__device__ __forceinline__ unsigned bf16pack(float a, float b) {
  unsigned ua = __float_as_uint(a); ua = (ua + 0x7FFFu + ((ua >> 16) & 1u)) >> 16;
  unsigned ub = __float_as_uint(b); ub = (ub + 0x7FFFu + ((ub >> 16) & 1u)) >> 16;
  return ua | (ub << 16);
}

// ---------------------------------------------------------------------------
// K1: normalize rows, cast to bf16. Fn: (B,N,384). Cn: (B,N,96) zero-padded.
// ---------------------------------------------------------------------------
__global__ __launch_bounds__(64) void norm_cast(const float* __restrict__ codes,
                                                const float* __restrict__ feats,
                                                unsigned short* __restrict__ Fn,
                                                unsigned short* __restrict__ Cn,
                                                float* __restrict__ invc) {
  const int row = blockIdx.x;            // 0 .. 8191
  const int lane = threadIdx.x;
  const float* f = feats + (size_t)row * 384;
  float2 v[3];
  float ss = 0.f;
#pragma unroll
  for (int j = 0; j < 3; ++j) {
    v[j] = *(const float2*)(f + j * 128 + lane * 2);
    ss = fmaf(v[j].x, v[j].x, ss);
    ss = fmaf(v[j].y, v[j].y, ss);
  }
#pragma unroll
  for (int m = 1; m <= 32; m <<= 1) ss += __shfl_xor(ss, m, 64);
  const float inv = rsqrtf(ss + 1e-8f);
  unsigned* Fo = (unsigned*)(Fn + (size_t)row * 384);
#pragma unroll
  for (int j = 0; j < 3; ++j)
    Fo[j * 64 + lane] = bf16pack(v[j].x * inv, v[j].y * inv);
  const float* c = codes + (size_t)row * 90;
  float2 cv = make_float2(0.f, 0.f);
  if (lane < 45) cv = *(const float2*)(c + lane * 2);
  float cs = fmaf(cv.x, cv.x, cv.y * cv.y);
#pragma unroll
  for (int m = 1; m <= 32; m <<= 1) cs += __shfl_xor(cs, m, 64);
  const float cinv = rsqrtf(cs + 1e-8f);
  const unsigned pc = (lane < 45) ? bf16pack(cv.x * cinv, cv.y * cinv) : 0u;
  if (lane < 48) ((unsigned*)(Cn + (size_t)row * 96))[lane] = pc;
  if (lane == 0) invc[row] = cinv;
}

// ---------------------------------------------------------------------------
// K2: feature similarities via 32x32x16 bf16 MFMA (swapped: D[m][q]) + top-7.
// 256 thr / 4 waves per block; wave w sweeps m in [w*1024,(w+1)*1024).
// A streamed through a single 12-frag chunk (2 K-chunks) to stay under 256
// VGPR (round-4 lesson: the 288-reg double-buffer spilled 295 MB to scratch).
// ---------------------------------------------------------------------------
__global__ __launch_bounds__(256, 2) void knn_mfma(const unsigned short* __restrict__ Fn,
                                                   int* __restrict__ knn_out) {
  __shared__ float cval[4][32][7];
  __shared__ int   cidx[4][32][7];
  const int g = blockIdx.x;              // 0..255
  const int b = g >> 7;
  const int q0 = (g & 127) * 32;
  const int tid = threadIdx.x;
  const int w = tid >> 6;                // 0..3
  const int lane = tid & 63;
  const int lo = lane & 31, hi = lane >> 5, hi4 = (lane >> 5) * 4;
  const unsigned short* Fb = Fn + (size_t)b * NPTS * 384;

  bf16x8 bfr[24];
  {
    const unsigned short* qr = Fb + (size_t)(q0 + lo) * 384 + hi * 8;
#pragma unroll
    for (int t = 0; t < 24; ++t) bfr[t] = *(const bf16x8*)(qr + t * 16);
  }
  float v7[7]; int i7[7]; float vmin = -1e30f; int pmin = 0;
#pragma unroll
  for (int t = 0; t < 7; ++t) { v7[t] = -1e30f; i7[t] = 0; }

  const int mbase = w * 1024;            // this wave's m-range
  const unsigned short* ar0 = Fb + (size_t)(mbase + lo) * 384 + hi * 8;

  for (int mt = 0; mt < 32; ++mt) {
    const unsigned short* ar = ar0 + (size_t)mt * 32 * 384;
    f32x16 acc = zero16();
    bf16x8 a[12];
#pragma unroll
    for (int kc = 0; kc < 2; ++kc) {
#pragma unroll
      for (int t = 0; t < 12; ++t) a[t] = *(const bf16x8*)(ar + (kc * 12 + t) * 16);
#pragma unroll
      for (int t = 0; t < 12; ++t)
        acc = __builtin_amdgcn_mfma_f32_32x32x16_bf16(a[t], bfr[kc * 12 + t], acc, 0, 0, 0);
    }
    const int mb = mbase + mt * 32 + hi4;
#pragma unroll
    for (int r = 0; r < 16; ++r) {
      const int m = mb + (r & 3) + 8 * (r >> 2);
      top7_insert(acc[r], m, v7, i7, vmin, pmin);
    }
  }

  // merge lane pairs (lane, lane^32) covering the same q-column
  float nv[7]; int ni[7]; float nvm = -1e30f; int npm = 0;
#pragma unroll
  for (int t = 0; t < 7; ++t) { nv[t] = -1e30f; ni[t] = 0; }
#pragma unroll
  for (int t = 0; t < 7; ++t) {
    float ov = __shfl_xor(v7[t], 32, 64);
    int   oi = __shfl_xor(i7[t], 32, 64);
    top7_insert(v7[t], i7[t], nv, ni, nvm, npm);
    top7_insert(ov, oi, nv, ni, nvm, npm);
  }
  if (lane < 32) {
#pragma unroll
    for (int t = 0; t < 7; ++t) { cval[w][lo][t] = nv[t]; cidx[w][lo][t] = ni[t]; }
  }
  __syncthreads();

  // final merge: 32 threads, one q each, scan 4 waves x 7 candidates
  if (tid < 32) {
    float fv[7]; int fi[7]; float fvm = -1e30f; int fpm = 0;
#pragma unroll
    for (int t = 0; t < 7; ++t) { fv[t] = -1e30f; fi[t] = 0; }
    for (int w2 = 0; w2 < 4; ++w2)
#pragma unroll
      for (int t = 0; t < 7; ++t)
        top7_insert(cval[w2][tid][t], cidx[w2][tid][t], fv, fi, fvm, fpm);
    // FORCE self (self-sim = 1 is always the reference max)
    const int q = q0 + tid;
    bool has = false;
#pragma unroll
    for (int t = 0; t < 7; ++t) has = has || (fi[t] == q);
    if (!has) {
      float mn = fv[0]; int mp = 0;
#pragma unroll
      for (int t = 1; t < 7; ++t)
        if (fv[t] < mn) { mn = fv[t]; mp = t; }
#pragma unroll
      for (int t = 0; t < 7; ++t)
        if (t == mp) fi[t] = q;
    }
    int* o = knn_out + ((size_t)b * NPTS + q) * 7;
#pragma unroll
    for (int t = 0; t < 7; ++t) o[t] = fi[t];
  }
}

// ---------------------------------------------------------------------------
// K3: code similarities -> fixed-max LSE (max logit == 10 from self-sim) +
// depth-Gaussian weighted sum. 4-wave m-split, LDS partial merge.
// ---------------------------------------------------------------------------
__global__ __launch_bounds__(256, 2) void lse_depth(const unsigned short* __restrict__ Cn,
                                                    const float* __restrict__ depth,
                                                    float* __restrict__ lse_out,
                                                    float* __restrict__ dpart) {
  __shared__ float lsep[4][32];
  __shared__ float depp[4];
  const int g = blockIdx.x;
  const int b = g >> 7;
  const int q0 = (g & 127) * 32;
  const int tid = threadIdx.x;
  const int w = tid >> 6;
  const int lane = tid & 63;
  const int lo = lane & 31, hi = lane >> 5, hi4 = (lane >> 5) * 4;
  const unsigned short* Cb = Cn + (size_t)b * NPTS * 96;
  const float* db = depth + b * NPTS;

  bf16x8 bfr[6];
  {
    const unsigned short* qr = Cb + (size_t)(q0 + lo) * 96 + hi * 8;
#pragma unroll
    for (int t = 0; t < 6; ++t) bfr[t] = *(const bf16x8*)(qr + t * 16);
  }
  const float dq = db[q0 + lo];
  float slse = 0.f, sdep = 0.f;

  const int mbase = w * 1024;
  const unsigned short* ar0 = Cb + (size_t)(mbase + lo) * 96 + hi * 8;

  for (int mt = 0; mt < 32; ++mt) {
    const unsigned short* ar = ar0 + (size_t)mt * 32 * 96;
    f32x16 acc = zero16();
    bf16x8 a[6];
#pragma unroll
    for (int t = 0; t < 6; ++t) a[t] = *(const bf16x8*)(ar + t * 16);
#pragma unroll
    for (int t = 0; t < 6; ++t)
      acc = __builtin_amdgcn_mfma_f32_32x32x16_bf16(a[t], bfr[t], acc, 0, 0, 0);
    float dvv[16];
#pragma unroll
    for (int k = 0; k < 4; ++k) {
      float4 dv = *(const float4*)(db + mbase + mt * 32 + hi4 + 8 * k);
      dvv[k * 4 + 0] = dv.x; dvv[k * 4 + 1] = dv.y;
      dvv[k * 4 + 2] = dv.z; dvv[k * 4 + 3] = dv.w;
    }
#pragma unroll
    for (int r = 0; r < 16; ++r) {
      const float s = acc[r];
      const float dd = dq - dvv[r];
      sdep += __expf(-2.f * dd * dd) * (1.f - s);
      slse += __expf(fmaf(s, 10.f, -10.f));
    }
  }

  slse += __shfl_xor(slse, 32, 64);
  if (lane < 32) lsep[w][lo] = slse;
#pragma unroll
  for (int m = 1; m <= 32; m <<= 1) sdep += __shfl_xor(sdep, m, 64);
  if (lane == 0) depp[w] = sdep;
  __syncthreads();
  if (tid < 32) {
    float tot = 0.f;
#pragma unroll
    for (int w2 = 0; w2 < 4; ++w2) tot += lsep[w2][tid];
    lse_out[(size_t)b * NPTS + q0 + tid] = 10.f + __logf(tot);
  }
  if (tid == 32) {
    float d = 0.f;
#pragma unroll
    for (int w2 = 0; w2 < 4; ++w2) d += depp[w2];
    dpart[g] = d;
  }
}

// ---------------------------------------------------------------------------
// K4: positive-pair code similarity in FP32 from raw codes. One wave per row.
// ---------------------------------------------------------------------------
__global__ __launch_bounds__(64) void gather_pos(const float* __restrict__ codes,
                                                 const float* __restrict__ invc,
                                                 const int* __restrict__ knn,
                                                 float* __restrict__ gpart) {
  const int n = blockIdx.x;              // 0..8191 (global row)
  const int b = n >> 12;
  const int lane = threadIdx.x;
  const float* cn = codes + (size_t)n * 90;
  float2 a = make_float2(0.f, 0.f);
  if (lane < 45) a = *(const float2*)(cn + lane * 2);
  const float inva = invc[n];
  float ssum = 0.f;
  for (int k = 0; k < 7; ++k) {
    const int m = knn[(size_t)n * 7 + k];
    const float* cm = codes + ((size_t)(b << 12) + m) * 90;
    float2 bb = make_float2(0.f, 0.f);
    if (lane < 45) bb = *(const float2*)(cm + lane * 2);
    float p = fmaf(a.x, bb.x, a.y * bb.y);
#pragma unroll
    for (int w = 1; w <= 32; w <<= 1) p += __shfl_xor(p, w, 64);
    ssum += p * inva * invc[(b << 12) + m];
  }
  if (lane == 0) gpart[n] = ssum;
}

// ---------------------------------------------------------------------------
// K5: finalize -> (l_stego, l_depthg, total)
// ---------------------------------------------------------------------------
__global__ __launch_bounds__(256) void finalize(const float* __restrict__ lse,
                                                const float* __restrict__ gpart,
                                                const float* __restrict__ dpart,
                                                float* __restrict__ out) {
  const int tid = threadIdx.x;
  float s1 = 0.f, s2 = 0.f;
  for (int i = tid; i < 2 * NPTS; i += 256) { s1 += lse[i]; s2 += gpart[i]; }
  float s3 = dpart[tid];
  __shared__ float r1[256], r2[256], r3[256];
  r1[tid] = s1; r2[tid] = s2; r3[tid] = s3;
  __syncthreads();
  for (int s = 128; s > 0; s >>= 1) {
    if (tid < s) { r1[tid] += r1[tid + s]; r2[tid] += r2[tid + s]; r3[tid] += r3[tid + s]; }
    __syncthreads();
  }
  if (tid == 0) {
    const float l_st = (7.f * r1[0] - 10.f * r2[0]) / 57344.f;
    const float l_dp = r3[0] / 33554432.f;
    out[0] = l_st;
    out[1] = l_dp;
    out[2] = l_st + 0.3f * l_dp;
  }
}

// ---------------------------------------------------------------------------
extern "C" void kernel_launch(void* const* d_in, const int* in_sizes, int n_in,
                              void* d_out, int out_size, void* d_ws, size_t ws_size,
                              hipStream_t stream) {
  (void)in_sizes; (void)n_in; (void)out_size; (void)ws_size;
  const float* codes = (const float*)d_in[0];   // (B,N,90)
  const float* feats = (const float*)d_in[1];   // (B,N,384)
  const float* depth = (const float*)d_in[2];   // (B,N)
  float* out = (float*)d_out;

  char* ws = (char*)d_ws;
  float* invc  = (float*)ws;                         // 32768 B  @ 0
  float* lse   = (float*)(ws + 32768);               // 32768 B
  float* dpart = (float*)(ws + 65536);               // 1024 B
  float* gpart = (float*)(ws + 66560);               // 32768 B
  int*   knn   = (int*)(ws + 99328);                 // 229376 B
  unsigned short* Cn = (unsigned short*)(ws + 328704);   // 1572864 B
  unsigned short* Fn = (unsigned short*)(ws + 1901568);  // 6291456 B (end 8193024)

  norm_cast<<<2 * NPTS, 64, 0, stream>>>(codes, feats, Fn, Cn, invc);
  knn_mfma<<<256, 256, 0, stream>>>(Fn, knn);
  lse_depth<<<256, 256, 0, stream>>>(Cn, depth, lse, dpart);
  gather_pos<<<2 * NPTS, 64, 0, stream>>>(codes, invc, knn, gpart);
  finalize<<<1, 256, 0, stream>>>(lse, gpart, dpart, out);
}

// Round 6
// 159.125 us; speedup vs baseline: 7.1587x; 1.4153x over previous
//
#include <hip/hip_runtime.h>
#include <math.h>

#define NPTS 4096

typedef __attribute__((ext_vector_type(8))) short bf16x8;
typedef __attribute__((ext_vector_type(16))) float f32x16;

// liveness pin: forbid rematerialization / load sinking (round-5 lesson:
// compiler demoted bfr[24] to per-iteration reloads, VGPR_Count=84)
#define KEEP(x) asm volatile("" : "+v"(x))

__device__ __forceinline__ f32x16 zero16() {
  f32x16 z;
#pragma unroll
  for (int i = 0; i < 16; ++i) z[i] = 0.f;
  return z;
}

// top-7 insertion, fully static register indexing (rule #20)
__device__ __forceinline__ void top7_insert(float v, int i, float* v7, int* i7,
                                            float& vmin, int& pmin) {
  if (v > vmin) {
#pragma unroll
    for (int t = 0; t < 7; ++t)
      if (t == pmin) { v7[t] = v; i7[t] = i; }
    vmin = v7[0]; pmin = 0;
#pragma unroll
    for (int t = 1; t < 7; ++t)
      if (v7[t] < vmin) { vmin = v7[t]; pmin = t; }
  }
}

__device__ __forceinline__ unsigned bf16pack(float a, float b) {
  unsigned ua = __float_as_uint(a); ua = (ua + 0x7FFFu + ((ua >> 16) & 1u)) >> 16;
  unsigned ub = __float_as_uint(b); ub = (ub + 0x7FFFu + ((ub >> 16) & 1u)) >> 16;
  return ua | (ub << 16);
}

// ---------------------------------------------------------------------------
// K1: normalize rows, cast to bf16. Fn: (B,N,384). Cn: (B,N,96) zero-padded.
// ---------------------------------------------------------------------------
__global__ __launch_bounds__(64) void norm_cast(const float* __restrict__ codes,
                                                const float* __restrict__ feats,
                                                unsigned short* __restrict__ Fn,
                                                unsigned short* __restrict__ Cn,
                                                float* __restrict__ invc) {
  const int row = blockIdx.x;            // 0 .. 8191
  const int lane = threadIdx.x;
  const float* f = feats + (size_t)row * 384;
  float2 v[3];
  float ss = 0.f;
#pragma unroll
  for (int j = 0; j < 3; ++j) {
    v[j] = *(const float2*)(f + j * 128 + lane * 2);
    ss = fmaf(v[j].x, v[j].x, ss);
    ss = fmaf(v[j].y, v[j].y, ss);
  }
#pragma unroll
  for (int m = 1; m <= 32; m <<= 1) ss += __shfl_xor(ss, m, 64);
  const float inv = rsqrtf(ss + 1e-8f);
  unsigned* Fo = (unsigned*)(Fn + (size_t)row * 384);
#pragma unroll
  for (int j = 0; j < 3; ++j)
    Fo[j * 64 + lane] = bf16pack(v[j].x * inv, v[j].y * inv);
  const float* c = codes + (size_t)row * 90;
  float2 cv = make_float2(0.f, 0.f);
  if (lane < 45) cv = *(const float2*)(c + lane * 2);
  float cs = fmaf(cv.x, cv.x, cv.y * cv.y);
#pragma unroll
  for (int m = 1; m <= 32; m <<= 1) cs += __shfl_xor(cs, m, 64);
  const float cinv = rsqrtf(cs + 1e-8f);
  const unsigned pc = (lane < 45) ? bf16pack(cv.x * cinv, cv.y * cinv) : 0u;
  if (lane < 48) ((unsigned*)(Cn + (size_t)row * 96))[lane] = pc;
  if (lane == 0) invc[row] = cinv;
}

// ---------------------------------------------------------------------------
// K2: feature similarities via 32x32x16 bf16 MFMA (swapped: D[m][q]) + top-7.
// 512 thr / 8 waves; wave w sweeps m in [w*512,(w+1)*512) = 16 tiles.
// A double-buffered in 12-frag chunks; all fragments pinned with KEEP.
// ---------------------------------------------------------------------------
__global__ __launch_bounds__(512, 1) void knn_mfma(const unsigned short* __restrict__ Fn,
                                                   int* __restrict__ knn_out) {
  __shared__ float cval[8][32][7];
  __shared__ int   cidx[8][32][7];
  const int g = blockIdx.x;              // 0..255
  const int b = g >> 7;
  const int q0 = (g & 127) * 32;
  const int tid = threadIdx.x;
  const int w = tid >> 6;                // 0..7
  const int lane = tid & 63;
  const int lo = lane & 31, hi = lane >> 5, hi4 = (lane >> 5) * 4;
  const unsigned short* Fb = Fn + (size_t)b * NPTS * 384;

  bf16x8 bfr[24];
  {
    const unsigned short* qr = Fb + (size_t)(q0 + lo) * 384 + hi * 8;
#pragma unroll
    for (int t = 0; t < 24; ++t) bfr[t] = *(const bf16x8*)(qr + t * 16);
#pragma unroll
    for (int t = 0; t < 24; ++t) KEEP(bfr[t]);
  }
  float v7[7]; int i7[7]; float vmin = -1e30f; int pmin = 0;
#pragma unroll
  for (int t = 0; t < 7; ++t) { v7[t] = -1e30f; i7[t] = 0; }

  const int mbase = w * 512;             // this wave's m-range: 16 tiles
  const unsigned short* ar0 = Fb + (size_t)(mbase + lo) * 384 + hi * 8;

  bf16x8 a0[12], a1[12];
  // prologue: a0 <- (mt=0, kc=0)
#pragma unroll
  for (int t = 0; t < 12; ++t) a0[t] = *(const bf16x8*)(ar0 + t * 16);
#pragma unroll
  for (int t = 0; t < 12; ++t) KEEP(a0[t]);

  for (int mt = 0; mt < 16; ++mt) {
    const unsigned short* art = ar0 + (size_t)mt * 32 * 384;
    // prefetch second K-half of this tile
#pragma unroll
    for (int t = 0; t < 12; ++t) a1[t] = *(const bf16x8*)(art + (12 + t) * 16);
#pragma unroll
    for (int t = 0; t < 12; ++t) KEEP(a1[t]);
    f32x16 acc = zero16();
#pragma unroll
    for (int t = 0; t < 12; ++t)
      acc = __builtin_amdgcn_mfma_f32_32x32x16_bf16(a0[t], bfr[t], acc, 0, 0, 0);
    // prefetch first K-half of next tile
    if (mt + 1 < 16) {
      const unsigned short* arn = ar0 + (size_t)(mt + 1) * 32 * 384;
#pragma unroll
      for (int t = 0; t < 12; ++t) a0[t] = *(const bf16x8*)(arn + t * 16);
#pragma unroll
      for (int t = 0; t < 12; ++t) KEEP(a0[t]);
    }
#pragma unroll
    for (int t = 0; t < 12; ++t)
      acc = __builtin_amdgcn_mfma_f32_32x32x16_bf16(a1[t], bfr[12 + t], acc, 0, 0, 0);
    const int mb = mbase + mt * 32 + hi4;
#pragma unroll
    for (int r = 0; r < 16; ++r) {
      const int m = mb + (r & 3) + 8 * (r >> 2);
      top7_insert(acc[r], m, v7, i7, vmin, pmin);
    }
  }

  // merge lane pairs (lane, lane^32) covering the same q-column
  float nv[7]; int ni[7]; float nvm = -1e30f; int npm = 0;
#pragma unroll
  for (int t = 0; t < 7; ++t) { nv[t] = -1e30f; ni[t] = 0; }
#pragma unroll
  for (int t = 0; t < 7; ++t) {
    float ov = __shfl_xor(v7[t], 32, 64);
    int   oi = __shfl_xor(i7[t], 32, 64);
    top7_insert(v7[t], i7[t], nv, ni, nvm, npm);
    top7_insert(ov, oi, nv, ni, nvm, npm);
  }
  if (lane < 32) {
#pragma unroll
    for (int t = 0; t < 7; ++t) { cval[w][lo][t] = nv[t]; cidx[w][lo][t] = ni[t]; }
  }
  __syncthreads();

  // final merge: 32 threads, one q each, scan 8 waves x 7 candidates
  if (tid < 32) {
    float fv[7]; int fi[7]; float fvm = -1e30f; int fpm = 0;
#pragma unroll
    for (int t = 0; t < 7; ++t) { fv[t] = -1e30f; fi[t] = 0; }
    for (int w2 = 0; w2 < 8; ++w2)
#pragma unroll
      for (int t = 0; t < 7; ++t)
        top7_insert(cval[w2][tid][t], cidx[w2][tid][t], fv, fi, fvm, fpm);
    // FORCE self (self-sim = 1 is always the reference max)
    const int q = q0 + tid;
    bool has = false;
#pragma unroll
    for (int t = 0; t < 7; ++t) has = has || (fi[t] == q);
    if (!has) {
      float mn = fv[0]; int mp = 0;
#pragma unroll
      for (int t = 1; t < 7; ++t)
        if (fv[t] < mn) { mn = fv[t]; mp = t; }
#pragma unroll
      for (int t = 0; t < 7; ++t)
        if (t == mp) fi[t] = q;
    }
    int* o = knn_out + ((size_t)b * NPTS + q) * 7;
#pragma unroll
    for (int t = 0; t < 7; ++t) o[t] = fi[t];
  }
}

// ---------------------------------------------------------------------------
// K3: code similarities -> fixed-max LSE (max logit == 10 from self-sim) +
// depth-Gaussian weighted sum. 8-wave m-split, double-buffered, pinned.
// ---------------------------------------------------------------------------
__global__ __launch_bounds__(512, 1) void lse_depth(const unsigned short* __restrict__ Cn,
                                                    const float* __restrict__ depth,
                                                    float* __restrict__ lse_out,
                                                    float* __restrict__ dpart) {
  __shared__ float lsep[8][32];
  __shared__ float depp[8];
  const int g = blockIdx.x;
  const int b = g >> 7;
  const int q0 = (g & 127) * 32;
  const int tid = threadIdx.x;
  const int w = tid >> 6;
  const int lane = tid & 63;
  const int lo = lane & 31, hi = lane >> 5, hi4 = (lane >> 5) * 4;
  const unsigned short* Cb = Cn + (size_t)b * NPTS * 96;
  const float* db = depth + b * NPTS;

  bf16x8 bfr[6];
  {
    const unsigned short* qr = Cb + (size_t)(q0 + lo) * 96 + hi * 8;
#pragma unroll
    for (int t = 0; t < 6; ++t) bfr[t] = *(const bf16x8*)(qr + t * 16);
#pragma unroll
    for (int t = 0; t < 6; ++t) KEEP(bfr[t]);
  }
  const float dq = db[q0 + lo];
  float slse = 0.f, sdep = 0.f;

  const int mbase = w * 512;             // 16 tiles
  const unsigned short* ar0 = Cb + (size_t)(mbase + lo) * 96 + hi * 8;

  bf16x8 a0[6], a1[6];
#pragma unroll
  for (int t = 0; t < 6; ++t) a0[t] = *(const bf16x8*)(ar0 + t * 16);
#pragma unroll
  for (int t = 0; t < 6; ++t) KEEP(a0[t]);

#define PROC3(A, MT)                                                           \
  {                                                                            \
    f32x16 acc = zero16();                                                     \
    _Pragma("unroll")                                                          \
    for (int t = 0; t < 6; ++t)                                                \
      acc = __builtin_amdgcn_mfma_f32_32x32x16_bf16(A[t], bfr[t], acc, 0, 0, 0); \
    float dvv[16];                                                             \
    _Pragma("unroll")                                                          \
    for (int k = 0; k < 4; ++k) {                                              \
      float4 dv = *(const float4*)(db + mbase + (MT) * 32 + hi4 + 8 * k);      \
      dvv[k * 4 + 0] = dv.x; dvv[k * 4 + 1] = dv.y;                            \
      dvv[k * 4 + 2] = dv.z; dvv[k * 4 + 3] = dv.w;                            \
    }                                                                          \
    _Pragma("unroll")                                                          \
    for (int r = 0; r < 16; ++r) {                                             \
      const float s = acc[r];                                                  \
      const float dd = dq - dvv[r];                                            \
      sdep += __expf(-2.f * dd * dd) * (1.f - s);                              \
      slse += __expf(fmaf(s, 10.f, -10.f));                                    \
    }                                                                          \
  }

  for (int mt = 0; mt < 16; mt += 2) {
    {
      const unsigned short* ar = ar0 + (size_t)(mt + 1) * 32 * 96;
#pragma unroll
      for (int t = 0; t < 6; ++t) a1[t] = *(const bf16x8*)(ar + t * 16);
#pragma unroll
      for (int t = 0; t < 6; ++t) KEEP(a1[t]);
    }
    PROC3(a0, mt)
    if (mt + 2 < 16) {
      const unsigned short* ar = ar0 + (size_t)(mt + 2) * 32 * 96;
#pragma unroll
      for (int t = 0; t < 6; ++t) a0[t] = *(const bf16x8*)(ar + t * 16);
#pragma unroll
      for (int t = 0; t < 6; ++t) KEEP(a0[t]);
    }
    PROC3(a1, mt + 1)
  }
#undef PROC3

  slse += __shfl_xor(slse, 32, 64);
  if (lane < 32) lsep[w][lo] = slse;
#pragma unroll
  for (int m = 1; m <= 32; m <<= 1) sdep += __shfl_xor(sdep, m, 64);
  if (lane == 0) depp[w] = sdep;
  __syncthreads();
  if (tid < 32) {
    float tot = 0.f;
#pragma unroll
    for (int w2 = 0; w2 < 8; ++w2) tot += lsep[w2][tid];
    lse_out[(size_t)b * NPTS + q0 + tid] = 10.f + __logf(tot);
  }
  if (tid == 32) {
    float d = 0.f;
#pragma unroll
    for (int w2 = 0; w2 < 8; ++w2) d += depp[w2];
    dpart[g] = d;
  }
}

// ---------------------------------------------------------------------------
// K4: positive-pair code similarity in FP32 from raw codes. One wave per row.
// ---------------------------------------------------------------------------
__global__ __launch_bounds__(64) void gather_pos(const float* __restrict__ codes,
                                                 const float* __restrict__ invc,
                                                 const int* __restrict__ knn,
                                                 float* __restrict__ gpart) {
  const int n = blockIdx.x;              // 0..8191 (global row)
  const int b = n >> 12;
  const int lane = threadIdx.x;
  const float* cn = codes + (size_t)n * 90;
  float2 a = make_float2(0.f, 0.f);
  if (lane < 45) a = *(const float2*)(cn + lane * 2);
  const float inva = invc[n];
  float ssum = 0.f;
  for (int k = 0; k < 7; ++k) {
    const int m = knn[(size_t)n * 7 + k];
    const float* cm = codes + ((size_t)(b << 12) + m) * 90;
    float2 bb = make_float2(0.f, 0.f);
    if (lane < 45) bb = *(const float2*)(cm + lane * 2);
    float p = fmaf(a.x, bb.x, a.y * bb.y);
#pragma unroll
    for (int w = 1; w <= 32; w <<= 1) p += __shfl_xor(p, w, 64);
    ssum += p * inva * invc[(b << 12) + m];
  }
  if (lane == 0) gpart[n] = ssum;
}

// ---------------------------------------------------------------------------
// K5: finalize -> (l_stego, l_depthg, total)
// ---------------------------------------------------------------------------
__global__ __launch_bounds__(256) void finalize(const float* __restrict__ lse,
                                                const float* __restrict__ gpart,
                                                const float* __restrict__ dpart,
                                                float* __restrict__ out) {
  const int tid = threadIdx.x;
  float s1 = 0.f, s2 = 0.f;
  for (int i = tid; i < 2 * NPTS; i += 256) { s1 += lse[i]; s2 += gpart[i]; }
  float s3 = dpart[tid];
  __shared__ float r1[256], r2[256], r3[256];
  r1[tid] = s1; r2[tid] = s2; r3[tid] = s3;
  __syncthreads();
  for (int s = 128; s > 0; s >>= 1) {
    if (tid < s) { r1[tid] += r1[tid + s]; r2[tid] += r2[tid + s]; r3[tid] += r3[tid + s]; }
    __syncthreads();
  }
  if (tid == 0) {
    const float l_st = (7.f * r1[0] - 10.f * r2[0]) / 57344.f;
    const float l_dp = r3[0] / 33554432.f;
    out[0] = l_st;
    out[1] = l_dp;
    out[2] = l_st + 0.3f * l_dp;
  }
}

// ---------------------------------------------------------------------------
extern "C" void kernel_launch(void* const* d_in, const int* in_sizes, int n_in,
                              void* d_out, int out_size, void* d_ws, size_t ws_size,
                              hipStream_t stream) {
  (void)in_sizes; (void)n_in; (void)out_size; (void)ws_size;
  const float* codes = (const float*)d_in[0];   // (B,N,90)
  const float* feats = (const float*)d_in[1];   // (B,N,384)
  const float* depth = (const float*)d_in[2];   // (B,N)
  float* out = (float*)d_out;

  char* ws = (char*)d_ws;
  float* invc  = (float*)ws;                         // 32768 B  @ 0
  float* lse   = (float*)(ws + 32768);               // 32768 B
  float* dpart = (float*)(ws + 65536);               // 1024 B
  float* gpart = (float*)(ws + 66560);               // 32768 B
  int*   knn   = (int*)(ws + 99328);                 // 229376 B
  unsigned short* Cn = (unsigned short*)(ws + 328704);   // 1572864 B
  unsigned short* Fn = (unsigned short*)(ws + 1901568);  // 6291456 B (end 8193024)

  norm_cast<<<2 * NPTS, 64, 0, stream>>>(codes, feats, Fn, Cn, invc);
  knn_mfma<<<256, 512, 0, stream>>>(Fn, knn);
  lse_depth<<<256, 512, 0, stream>>>(Cn, depth, lse, dpart);
  gather_pos<<<2 * NPTS, 64, 0, stream>>>(codes, invc, knn, gpart);
  finalize<<<1, 256, 0, stream>>>(lse, gpart, dpart, out);
}

// Round 7
// 119.679 us; speedup vs baseline: 9.5182x; 1.3296x over previous
//
#include <hip/hip_runtime.h>
#include <math.h>

#define NPTS 4096

typedef __attribute__((ext_vector_type(8))) short bf16x8;
typedef __attribute__((ext_vector_type(16))) float f32x16;

// liveness pin: forbid rematerialization / load sinking (round-5 lesson)
#define KEEP(x) asm volatile("" : "+v"(x))

__device__ __forceinline__ f32x16 zero16() {
  f32x16 z;
#pragma unroll
  for (int i = 0; i < 16; ++i) z[i] = 0.f;
  return z;
}

// top-7 insertion, fully static register indexing (rule #20)
__device__ __forceinline__ void top7_insert(float v, int i, float* v7, int* i7,
                                            float& vmin, int& pmin) {
  if (v > vmin) {
#pragma unroll
    for (int t = 0; t < 7; ++t)
      if (t == pmin) { v7[t] = v; i7[t] = i; }
    vmin = v7[0]; pmin = 0;
#pragma unroll
    for (int t = 1; t < 7; ++t)
      if (v7[t] < vmin) { vmin = v7[t]; pmin = t; }
  }
}

__device__ __forceinline__ unsigned bf16pack(float a, float b) {
  unsigned ua = __float_as_uint(a); ua = (ua + 0x7FFFu + ((ua >> 16) & 1u)) >> 16;
  unsigned ub = __float_as_uint(b); ub = (ub + 0x7FFFu + ((ub >> 16) & 1u)) >> 16;
  return ua | (ub << 16);
}

// ---------------------------------------------------------------------------
// K1: normalize + cast + write FRAGMENT-MAJOR layout.
// Fsw[b][mt][kc(24)][lane(64)][8elem]  (1 KB fragment blocks, 24 KB per tile)
// Csw[b][mt][kc(6)][lane(64)][8elem]
// Fragment (kc, lane l) holds row (l&31) elems kc*16 + (l>>5)*8 + 0..7, i.e.
// exactly the 32x32x16 MFMA A/B fragment -> hot-kernel loads are lane-contiguous.
// Lane j (<48) of row r owns elems [8j, 8j+8) = frag kc=j>>1, slot (j&1)*32+(r&31).
// ---------------------------------------------------------------------------
__global__ __launch_bounds__(64) void norm_cast(const float* __restrict__ codes,
                                                const float* __restrict__ feats,
                                                unsigned short* __restrict__ Fsw,
                                                unsigned short* __restrict__ Csw,
                                                float* __restrict__ invc) {
  const int row = blockIdx.x;            // 0 .. 8191
  const int lane = threadIdx.x;
  const int b = row >> 12, mt = (row >> 5) & 127, rl = row & 31;

  // features: 384 floats, lane j<48 reads elems [8j, 8j+8)
  const float* f = feats + (size_t)row * 384;
  float v[8];
  float ss = 0.f;
  if (lane < 48) {
    float4 p0 = *(const float4*)(f + lane * 8);
    float4 p1 = *(const float4*)(f + lane * 8 + 4);
    v[0] = p0.x; v[1] = p0.y; v[2] = p0.z; v[3] = p0.w;
    v[4] = p1.x; v[5] = p1.y; v[6] = p1.z; v[7] = p1.w;
#pragma unroll
    for (int e = 0; e < 8; ++e) ss = fmaf(v[e], v[e], ss);
  }
#pragma unroll
  for (int m = 1; m <= 32; m <<= 1) ss += __shfl_xor(ss, m, 64);
  const float inv = rsqrtf(ss + 1e-8f);
  if (lane < 48) {
    uint4 o;
    o.x = bf16pack(v[0] * inv, v[1] * inv);
    o.y = bf16pack(v[2] * inv, v[3] * inv);
    o.z = bf16pack(v[4] * inv, v[5] * inv);
    o.w = bf16pack(v[6] * inv, v[7] * inv);
    const int kc = lane >> 1, hs = lane & 1;
    *(uint4*)(Fsw + (((size_t)(b * 128 + mt) * 24 + kc) << 9) + (hs * 32 + rl) * 8) = o;
  }

  // codes: 90 floats (pad to 96), lane j<12 owns elems [8j, 8j+8)
  const float* c = codes + (size_t)row * 90;
  float cv[8];
#pragma unroll
  for (int e = 0; e < 8; ++e) cv[e] = 0.f;
  if (lane < 11) {
    float4 p0 = *(const float4*)(c + lane * 8);
    float4 p1 = *(const float4*)(c + lane * 8 + 4);
    cv[0] = p0.x; cv[1] = p0.y; cv[2] = p0.z; cv[3] = p0.w;
    cv[4] = p1.x; cv[5] = p1.y; cv[6] = p1.z; cv[7] = p1.w;
  } else if (lane == 11) {
    cv[0] = c[88]; cv[1] = c[89];
  }
  float cs = 0.f;
#pragma unroll
  for (int e = 0; e < 8; ++e) cs = fmaf(cv[e], cv[e], cs);
#pragma unroll
  for (int m = 1; m <= 32; m <<= 1) cs += __shfl_xor(cs, m, 64);
  const float cinv = rsqrtf(cs + 1e-8f);
  if (lane < 12) {
    uint4 o;
    o.x = bf16pack(cv[0] * cinv, cv[1] * cinv);
    o.y = bf16pack(cv[2] * cinv, cv[3] * cinv);
    o.z = bf16pack(cv[4] * cinv, cv[5] * cinv);
    o.w = bf16pack(cv[6] * cinv, cv[7] * cinv);
    const int kc = lane >> 1, hs = lane & 1;
    *(uint4*)(Csw + (((size_t)(b * 128 + mt) * 6 + kc) << 9) + (hs * 32 + rl) * 8) = o;
  }
  if (lane == 0) invc[row] = cinv;
}

// ---------------------------------------------------------------------------
// K2: feature similarities via 32x32x16 bf16 MFMA (swapped: D[m][q]) + top-7.
// Fragment-major loads: base + t*512 ushorts + lane*8 -> fully coalesced.
// b = g&1 so each XCD's L2 holds only one batch panel (3 MB < 4 MB).
// ---------------------------------------------------------------------------
__global__ __launch_bounds__(512, 1) void knn_mfma(const unsigned short* __restrict__ Fsw,
                                                   int* __restrict__ knn_out) {
  __shared__ float cval[8][32][7];
  __shared__ int   cidx[8][32][7];
  const int g = blockIdx.x;              // 0..255
  const int b = g & 1;
  const int qt = g >> 1;                 // q-tile 0..127
  const int q0 = qt * 32;
  const int tid = threadIdx.x;
  const int w = tid >> 6;                // 0..7
  const int lane = tid & 63;
  const int lo = lane & 31, hi4 = (lane >> 5) * 4;
  const unsigned short* Fb = Fsw + (size_t)b * 128 * 24 * 512;

  bf16x8 bfr[24];
  {
    const unsigned short* qb = Fb + ((size_t)qt * 24) * 512 + lane * 8;
#pragma unroll
    for (int t = 0; t < 24; ++t) bfr[t] = *(const bf16x8*)(qb + t * 512);
#pragma unroll
    for (int t = 0; t < 24; ++t) KEEP(bfr[t]);
  }
  float v7[7]; int i7[7]; float vmin = -1e30f; int pmin = 0;
#pragma unroll
  for (int t = 0; t < 7; ++t) { v7[t] = -1e30f; i7[t] = 0; }

  // wave w sweeps m-tiles [w*16, w*16+16)
  const unsigned short* ab = Fb + ((size_t)(w * 16) * 24) * 512 + lane * 8;

  bf16x8 a0[12], a1[12];
#pragma unroll
  for (int t = 0; t < 12; ++t) a0[t] = *(const bf16x8*)(ab + t * 512);
#pragma unroll
  for (int t = 0; t < 12; ++t) KEEP(a0[t]);

  for (int mt = 0; mt < 16; ++mt) {
    const unsigned short* art = ab + (size_t)mt * 24 * 512;
    // prefetch second K-half of this tile
#pragma unroll
    for (int t = 0; t < 12; ++t) a1[t] = *(const bf16x8*)(art + (12 + t) * 512);
#pragma unroll
    for (int t = 0; t < 12; ++t) KEEP(a1[t]);
    f32x16 acc = zero16();
#pragma unroll
    for (int t = 0; t < 12; ++t)
      acc = __builtin_amdgcn_mfma_f32_32x32x16_bf16(a0[t], bfr[t], acc, 0, 0, 0);
    // prefetch first K-half of next tile
    if (mt + 1 < 16) {
      const unsigned short* arn = ab + (size_t)(mt + 1) * 24 * 512;
#pragma unroll
      for (int t = 0; t < 12; ++t) a0[t] = *(const bf16x8*)(arn + t * 512);
#pragma unroll
      for (int t = 0; t < 12; ++t) KEEP(a0[t]);
    }
#pragma unroll
    for (int t = 0; t < 12; ++t)
      acc = __builtin_amdgcn_mfma_f32_32x32x16_bf16(a1[t], bfr[12 + t], acc, 0, 0, 0);
    const int mb = (w * 16 + mt) * 32 + hi4;
#pragma unroll
    for (int r = 0; r < 16; ++r) {
      const int m = mb + (r & 3) + 8 * (r >> 2);
      top7_insert(acc[r], m, v7, i7, vmin, pmin);
    }
  }

  // merge lane pairs (lane, lane^32) covering the same q-column
  float nv[7]; int ni[7]; float nvm = -1e30f; int npm = 0;
#pragma unroll
  for (int t = 0; t < 7; ++t) { nv[t] = -1e30f; ni[t] = 0; }
#pragma unroll
  for (int t = 0; t < 7; ++t) {
    float ov = __shfl_xor(v7[t], 32, 64);
    int   oi = __shfl_xor(i7[t], 32, 64);
    top7_insert(v7[t], i7[t], nv, ni, nvm, npm);
    top7_insert(ov, oi, nv, ni, nvm, npm);
  }
  if (lane < 32) {
#pragma unroll
    for (int t = 0; t < 7; ++t) { cval[w][lo][t] = nv[t]; cidx[w][lo][t] = ni[t]; }
  }
  __syncthreads();

  // final merge: 32 threads, one q each, scan 8 waves x 7 candidates
  if (tid < 32) {
    float fv[7]; int fi[7]; float fvm = -1e30f; int fpm = 0;
#pragma unroll
    for (int t = 0; t < 7; ++t) { fv[t] = -1e30f; fi[t] = 0; }
    for (int w2 = 0; w2 < 8; ++w2)
#pragma unroll
      for (int t = 0; t < 7; ++t)
        top7_insert(cval[w2][tid][t], cidx[w2][tid][t], fv, fi, fvm, fpm);
    // FORCE self (self-sim = 1 is always the reference max)
    const int q = q0 + tid;
    bool has = false;
#pragma unroll
    for (int t = 0; t < 7; ++t) has = has || (fi[t] == q);
    if (!has) {
      float mn = fv[0]; int mp = 0;
#pragma unroll
      for (int t = 1; t < 7; ++t)
        if (fv[t] < mn) { mn = fv[t]; mp = t; }
#pragma unroll
      for (int t = 0; t < 7; ++t)
        if (t == mp) fi[t] = q;
    }
    int* o = knn_out + ((size_t)b * NPTS + q) * 7;
#pragma unroll
    for (int t = 0; t < 7; ++t) o[t] = fi[t];
  }
}

// ---------------------------------------------------------------------------
// K3: code similarities -> fixed-max LSE (self logit = 10 dominates; LSE with
// fixed shift 10 is mathematically exact) + depth-Gaussian weighted sum.
// ---------------------------------------------------------------------------
__global__ __launch_bounds__(512, 1) void lse_depth(const unsigned short* __restrict__ Csw,
                                                    const float* __restrict__ depth,
                                                    float* __restrict__ lse_out,
                                                    float* __restrict__ dpart) {
  __shared__ float lsep[8][32];
  __shared__ float depp[8];
  const int g = blockIdx.x;
  const int b = g & 1;
  const int qt = g >> 1;
  const int q0 = qt * 32;
  const int tid = threadIdx.x;
  const int w = tid >> 6;
  const int lane = tid & 63;
  const int lo = lane & 31, hi4 = (lane >> 5) * 4;
  const unsigned short* Cb = Csw + (size_t)b * 128 * 6 * 512;
  const float* db = depth + b * NPTS;

  bf16x8 bfr[6];
  {
    const unsigned short* qb = Cb + ((size_t)qt * 6) * 512 + lane * 8;
#pragma unroll
    for (int t = 0; t < 6; ++t) bfr[t] = *(const bf16x8*)(qb + t * 512);
#pragma unroll
    for (int t = 0; t < 6; ++t) KEEP(bfr[t]);
  }
  const float dq = db[q0 + lo];
  float slse = 0.f, sdep = 0.f;

  const int mbase = w * 512;             // 16 tiles
  const unsigned short* ab = Cb + ((size_t)(w * 16) * 6) * 512 + lane * 8;

  bf16x8 a0[6], a1[6];
#pragma unroll
  for (int t = 0; t < 6; ++t) a0[t] = *(const bf16x8*)(ab + t * 512);
#pragma unroll
  for (int t = 0; t < 6; ++t) KEEP(a0[t]);

#define PROC3(A, MT)                                                           \
  {                                                                            \
    f32x16 acc = zero16();                                                     \
    _Pragma("unroll")                                                          \
    for (int t = 0; t < 6; ++t)                                                \
      acc = __builtin_amdgcn_mfma_f32_32x32x16_bf16(A[t], bfr[t], acc, 0, 0, 0); \
    float dvv[16];                                                             \
    _Pragma("unroll")                                                          \
    for (int k = 0; k < 4; ++k) {                                              \
      float4 dv = *(const float4*)(db + mbase + (MT) * 32 + hi4 + 8 * k);      \
      dvv[k * 4 + 0] = dv.x; dvv[k * 4 + 1] = dv.y;                            \
      dvv[k * 4 + 2] = dv.z; dvv[k * 4 + 3] = dv.w;                            \
    }                                                                          \
    _Pragma("unroll")                                                          \
    for (int r = 0; r < 16; ++r) {                                             \
      const float s = acc[r];                                                  \
      const float dd = dq - dvv[r];                                            \
      sdep += __expf(-2.f * dd * dd) * (1.f - s);                              \
      slse += __expf(fmaf(s, 10.f, -10.f));                                    \
    }                                                                          \
  }

  for (int mt = 0; mt < 16; mt += 2) {
    {
      const unsigned short* ar = ab + (size_t)(mt + 1) * 6 * 512;
#pragma unroll
      for (int t = 0; t < 6; ++t) a1[t] = *(const bf16x8*)(ar + t * 512);
#pragma unroll
      for (int t = 0; t < 6; ++t) KEEP(a1[t]);
    }
    PROC3(a0, mt)
    if (mt + 2 < 16) {
      const unsigned short* ar = ab + (size_t)(mt + 2) * 6 * 512;
#pragma unroll
      for (int t = 0; t < 6; ++t) a0[t] = *(const bf16x8*)(ar + t * 512);
#pragma unroll
      for (int t = 0; t < 6; ++t) KEEP(a0[t]);
    }
    PROC3(a1, mt + 1)
  }
#undef PROC3

  slse += __shfl_xor(slse, 32, 64);
  if (lane < 32) lsep[w][lo] = slse;
#pragma unroll
  for (int m = 1; m <= 32; m <<= 1) sdep += __shfl_xor(sdep, m, 64);
  if (lane == 0) depp[w] = sdep;
  __syncthreads();
  if (tid < 32) {
    float tot = 0.f;
#pragma unroll
    for (int w2 = 0; w2 < 8; ++w2) tot += lsep[w2][tid];
    lse_out[(size_t)b * NPTS + q0 + tid] = 10.f + __logf(tot);
  }
  if (tid == 32) {
    float d = 0.f;
#pragma unroll
    for (int w2 = 0; w2 < 8; ++w2) d += depp[w2];
    dpart[g] = d;
  }
}

// ---------------------------------------------------------------------------
// K4: positive-pair code similarity in FP32 from raw codes. One wave per row.
// ---------------------------------------------------------------------------
__global__ __launch_bounds__(64) void gather_pos(const float* __restrict__ codes,
                                                 const float* __restrict__ invc,
                                                 const int* __restrict__ knn,
                                                 float* __restrict__ gpart) {
  const int n = blockIdx.x;              // 0..8191 (global row)
  const int b = n >> 12;
  const int lane = threadIdx.x;
  const float* cn = codes + (size_t)n * 90;
  float2 a = make_float2(0.f, 0.f);
  if (lane < 45) a = *(const float2*)(cn + lane * 2);
  const float inva = invc[n];
  float ssum = 0.f;
  for (int k = 0; k < 7; ++k) {
    const int m = knn[(size_t)n * 7 + k];
    const float* cm = codes + ((size_t)(b << 12) + m) * 90;
    float2 bb = make_float2(0.f, 0.f);
    if (lane < 45) bb = *(const float2*)(cm + lane * 2);
    float p = fmaf(a.x, bb.x, a.y * bb.y);
#pragma unroll
    for (int w = 1; w <= 32; w <<= 1) p += __shfl_xor(p, w, 64);
    ssum += p * inva * invc[(b << 12) + m];
  }
  if (lane == 0) gpart[n] = ssum;
}

// ---------------------------------------------------------------------------
// K5: finalize -> (l_stego, l_depthg, total)
// ---------------------------------------------------------------------------
__global__ __launch_bounds__(256) void finalize(const float* __restrict__ lse,
                                                const float* __restrict__ gpart,
                                                const float* __restrict__ dpart,
                                                float* __restrict__ out) {
  const int tid = threadIdx.x;
  float s1 = 0.f, s2 = 0.f;
  for (int i = tid; i < 2 * NPTS; i += 256) { s1 += lse[i]; s2 += gpart[i]; }
  float s3 = dpart[tid];
  __shared__ float r1[256], r2[256], r3[256];
  r1[tid] = s1; r2[tid] = s2; r3[tid] = s3;
  __syncthreads();
  for (int s = 128; s > 0; s >>= 1) {
    if (tid < s) { r1[tid] += r1[tid + s]; r2[tid] += r2[tid + s]; r3[tid] += r3[tid + s]; }
    __syncthreads();
  }
  if (tid == 0) {
    const float l_st = (7.f * r1[0] - 10.f * r2[0]) / 57344.f;
    const float l_dp = r3[0] / 33554432.f;
    out[0] = l_st;
    out[1] = l_dp;
    out[2] = l_st + 0.3f * l_dp;
  }
}

// ---------------------------------------------------------------------------
extern "C" void kernel_launch(void* const* d_in, const int* in_sizes, int n_in,
                              void* d_out, int out_size, void* d_ws, size_t ws_size,
                              hipStream_t stream) {
  (void)in_sizes; (void)n_in; (void)out_size; (void)ws_size;
  const float* codes = (const float*)d_in[0];   // (B,N,90)
  const float* feats = (const float*)d_in[1];   // (B,N,384)
  const float* depth = (const float*)d_in[2];   // (B,N)
  float* out = (float*)d_out;

  char* ws = (char*)d_ws;
  float* invc  = (float*)ws;                         // 32768 B  @ 0
  float* lse   = (float*)(ws + 32768);               // 32768 B
  float* dpart = (float*)(ws + 65536);               // 1024 B
  float* gpart = (float*)(ws + 66560);               // 32768 B
  int*   knn   = (int*)(ws + 99328);                 // 229376 B
  unsigned short* Csw = (unsigned short*)(ws + 328704);   // 1572864 B
  unsigned short* Fsw = (unsigned short*)(ws + 1901568);  // 6291456 B (end 8193024)

  norm_cast<<<2 * NPTS, 64, 0, stream>>>(codes, feats, Fsw, Csw, invc);
  knn_mfma<<<256, 512, 0, stream>>>(Fsw, knn);
  lse_depth<<<256, 512, 0, stream>>>(Csw, depth, lse, dpart);
  gather_pos<<<2 * NPTS, 64, 0, stream>>>(codes, invc, knn, gpart);
  finalize<<<1, 256, 0, stream>>>(lse, gpart, dpart, out);
}